// Round 8
// baseline (261.442 us; speedup 1.0000x reference)
//
#include <hip/hip_runtime.h>
#include <math.h>

#define NUM_CLASSES 100000
#define EMB 512
#define BATCH 512

/* fast path */
#define BNF 32                        /* classes per chunk */
#define NCHUNK (NUM_CLASSES / BNF)    /* 3125, exact — no tail */
#define GRID_F 512                    /* 2 blocks/CU */
/* fallback path */
#define BN 64
#define NBLK ((NUM_CLASSES + BN - 1) / BN)
#define GRID_S 256

#define RBLK 64

// ArcFace constants (margin m=0.3, scale s=120)
#define S_SCALE 120.0f
#define COS_M   0.9553364891256061f
#define SIN_M   0.29552020666133955f
#define TH_C   (-0.9553364891256061f)
#define MM_C    0.08865606199840187f

typedef short bf8 __attribute__((ext_vector_type(8)));   // 8 x bf16
typedef float f4  __attribute__((ext_vector_type(4)));   // MFMA accumulator

__device__ __forceinline__ unsigned short f2bf(float f) {
    union { float f; unsigned u; } a; a.f = f;
    unsigned r = a.u + 0x7fffu + ((a.u >> 16) & 1u);
    return (unsigned short)(r >> 16);
}

// ---------------------------------------------------------------------------
// k_normx: L2-normalize rows of x (f32) -> bf16, one wave per row.
// ---------------------------------------------------------------------------
__global__ __launch_bounds__(256) void k_normx(const float* __restrict__ x,
                                               unsigned short* __restrict__ xb) {
    int row  = blockIdx.x * 4 + (threadIdx.x >> 6);
    int lane = threadIdx.x & 63;
    const float4* xr = (const float4*)(x + (size_t)row * EMB);
    float4 a = xr[lane * 2];
    float4 b = xr[lane * 2 + 1];
    float ss = a.x*a.x + a.y*a.y + a.z*a.z + a.w*a.w
             + b.x*b.x + b.y*b.y + b.z*b.z + b.w*b.w;
#pragma unroll
    for (int d = 1; d < 64; d <<= 1) ss += __shfl_xor(ss, d);
    float rn = 1.0f / fmaxf(sqrtf(ss), 1e-12f);
    int4 o;
    o.x = f2bf(a.x * rn) | (f2bf(a.y * rn) << 16);
    o.y = f2bf(a.z * rn) | (f2bf(a.w * rn) << 16);
    o.z = f2bf(b.x * rn) | (f2bf(b.y * rn) << 16);
    o.w = f2bf(b.z * rn) | (f2bf(b.w * rn) << 16);
    ((int4*)(xb + (size_t)row * EMB))[lane] = o;
}

// ---------------------------------------------------------------------------
// k_tgt: exact f32 target logit per row: s*cos and s*phi at the label.
// ---------------------------------------------------------------------------
__global__ __launch_bounds__(512) void k_tgt(const float* __restrict__ x,
                                             const float* __restrict__ W,
                                             const long long* __restrict__ label,
                                             float* __restrict__ tcos,
                                             float* __restrict__ tphi) {
    int m    = blockIdx.x * 8 + (threadIdx.x >> 6);
    int lane = threadIdx.x & 63;
    int lb   = (int)label[m];
    const float4* xr = (const float4*)(x + (size_t)m  * EMB);
    const float4* wr = (const float4*)(W + (size_t)lb * EMB);
    float sx = 0.f, sw = 0.f, sd = 0.f;
#pragma unroll
    for (int q = 0; q < 2; ++q) {
        float4 a = xr[lane * 2 + q];
        float4 b = wr[lane * 2 + q];
        sx += a.x*a.x + a.y*a.y + a.z*a.z + a.w*a.w;
        sw += b.x*b.x + b.y*b.y + b.z*b.z + b.w*b.w;
        sd += a.x*b.x + a.y*b.y + a.z*b.z + a.w*b.w;
    }
#pragma unroll
    for (int d = 1; d < 64; d <<= 1) {
        sx += __shfl_xor(sx, d);
        sw += __shfl_xor(sw, d);
        sd += __shfl_xor(sd, d);
    }
    if (lane == 0) {
        float cv = sd / (fmaxf(sqrtf(sx), 1e-12f) * fmaxf(sqrtf(sw), 1e-12f));
        float sine = sqrtf(fmaxf(0.f, 1.f - cv * cv));
        float phi  = cv * COS_M - sine * SIN_M;
        if (!(cv > TH_C)) phi = cv - MM_C;
        tcos[m] = S_SCALE * cv;
        tphi[m] = S_SCALE * phi;
    }
}

// ---------------------------------------------------------------------------
// k_prep: W f32 -> Wb bf16 with S/||w|| folded in, PRE-SWIZZLED so k_mainF's
// staging is a linear memcpy-to-LDS and its swizzled ds_reads see the right
// bytes (both-sides-or-neither rule). One wave per class.
// ---------------------------------------------------------------------------
__global__ __launch_bounds__(256) void k_prep(const float* __restrict__ W,
                                              unsigned short* __restrict__ Wb) {
    int w    = blockIdx.x * 4 + (threadIdx.x >> 6);
    int lane = threadIdx.x & 63;
    const float4* r = (const float4*)(W + (size_t)w * EMB);
    float4 a = r[lane * 2];
    float4 b = r[lane * 2 + 1];
    float ss = a.x*a.x + a.y*a.y + a.z*a.z + a.w*a.w
             + b.x*b.x + b.y*b.y + b.z*b.z + b.w*b.w;
#pragma unroll
    for (int d = 1; d < 64; d <<= 1) ss += __shfl_xor(ss, d);
    float rn = S_SCALE / fmaxf(sqrtf(ss), 1e-12f);
    uint4 o;
    o.x = f2bf(a.x*rn) | (f2bf(a.y*rn) << 16);
    o.y = f2bf(a.z*rn) | (f2bf(a.w*rn) << 16);
    o.z = f2bf(b.x*rn) | (f2bf(b.y*rn) << 16);
    o.w = f2bf(b.z*rn) | (f2bf(b.w*rn) << 16);
    // lane's 16B unit index = lane; store at XOR-swizzled unit position
    *(uint4*)((char*)Wb + (size_t)w * 1024 + ((unsigned)(lane ^ (w & 7)) << 4)) = o;
}

// ---------------------------------------------------------------------------
// k_mainF: persistent streaming GEMM + per-lane online LSE.
// 512 blocks x 512 threads (8 waves, 2 blocks/CU). LDS 2 x 32 KiB dbuf.
// Per 32-class chunk: issue next chunk's 4 global_load_lds -> counted
// s_waitcnt vmcnt(4) (prefetch stays in flight across raw s_barrier) ->
// k-loop (wave = 64 rows x 32 cls: 2 swizzled B ds_read_b128 + 4 A global
// b128 + 8 MFMA per k-step) -> branchless online (M,S) update in regs ->
// barrier. Zero VALU staging, zero LDS softmax state, 2 barriers/chunk.
// ---------------------------------------------------------------------------
__global__ __launch_bounds__(512, 4) void k_mainF(
        const unsigned short* __restrict__ Wb,
        const unsigned short* __restrict__ xb,
        float2* __restrict__ pms) {
    __shared__ __align__(16) unsigned short Bl[2][BNF * EMB];  // 2 x 32 KiB

    const int tid  = threadIdx.x;
    const int lane = tid & 63;
    const int wv   = tid >> 6;        // wave: rows wv*64 .. +64
    const int l15  = lane & 15;
    const int lg   = lane >> 4;
    const unsigned short* xp = xb + (size_t)(wv * 64 + l15) * EMB;

    float Mr[4][4], Sr[4][4];
#pragma unroll
    for (int mf = 0; mf < 4; ++mf)
#pragma unroll
        for (int i = 0; i < 4; ++i) { Mr[mf][i] = -1e38f; Sr[mf][i] = 0.0f; }

    const char* WbB = (const char*)Wb;
    auto issue = [&](int ci, int b) {
        const char* src = WbB + (size_t)ci * (BNF * EMB * 2) + wv * 1024 + lane * 16;
        char* dst = (char*)&Bl[b][0] + wv * 1024;   // wave-uniform base
#pragma unroll
        for (int r2 = 0; r2 < 4; ++r2)
            __builtin_amdgcn_global_load_lds(
                (const __attribute__((address_space(1))) unsigned int*)(src + r2 * 8192),
                (__attribute__((address_space(3))) unsigned int*)(dst + r2 * 8192),
                16, 0, 0);
    };

    issue(blockIdx.x, 0);
    int buf = 0;
    for (int ci = blockIdx.x; ci < NCHUNK; ci += GRID_F) {
        int cn = ci + GRID_F;
        if (cn < NCHUNK) {
            issue(cn, buf ^ 1);
            asm volatile("s_waitcnt vmcnt(4)" ::: "memory");   // current buf done
        } else {
            asm volatile("s_waitcnt vmcnt(0)" ::: "memory");
        }
        __builtin_amdgcn_sched_barrier(0);
        __builtin_amdgcn_s_barrier();
        __builtin_amdgcn_sched_barrier(0);

        // ---- k-loop: 64 rows x 32 classes per wave ----
        f4 acc[4][2];
#pragma unroll
        for (int mf = 0; mf < 4; ++mf)
#pragma unroll
            for (int nf = 0; nf < 2; ++nf)
#pragma unroll
                for (int i = 0; i < 4; ++i) acc[mf][nf][i] = 0.0f;

        const char* BB = (const char*)&Bl[buf][0];
#pragma unroll 2
        for (int k0 = 0; k0 < EMB; k0 += 32) {
            int u  = (k0 >> 3) + lg;                       // 16B unit in row
            int sx = ((u ^ (l15 & 7)) << 4);               // swizzled byte off
            bf8 b0 = *(const bf8*)(BB + l15 * 1024 + sx);
            bf8 b1 = *(const bf8*)(BB + (16 + l15) * 1024 + sx);
            bf8 a0 = *(const bf8*)(xp + k0 + lg * 8);
            bf8 a1 = *(const bf8*)(xp + 16 * EMB + k0 + lg * 8);
            bf8 a2 = *(const bf8*)(xp + 32 * EMB + k0 + lg * 8);
            bf8 a3 = *(const bf8*)(xp + 48 * EMB + k0 + lg * 8);
            acc[0][0] = __builtin_amdgcn_mfma_f32_16x16x32_bf16(a0, b0, acc[0][0], 0, 0, 0);
            acc[0][1] = __builtin_amdgcn_mfma_f32_16x16x32_bf16(a0, b1, acc[0][1], 0, 0, 0);
            acc[1][0] = __builtin_amdgcn_mfma_f32_16x16x32_bf16(a1, b0, acc[1][0], 0, 0, 0);
            acc[1][1] = __builtin_amdgcn_mfma_f32_16x16x32_bf16(a1, b1, acc[1][1], 0, 0, 0);
            acc[2][0] = __builtin_amdgcn_mfma_f32_16x16x32_bf16(a2, b0, acc[2][0], 0, 0, 0);
            acc[2][1] = __builtin_amdgcn_mfma_f32_16x16x32_bf16(a2, b1, acc[2][1], 0, 0, 0);
            acc[3][0] = __builtin_amdgcn_mfma_f32_16x16x32_bf16(a3, b0, acc[3][0], 0, 0, 0);
            acc[3][1] = __builtin_amdgcn_mfma_f32_16x16x32_bf16(a3, b1, acc[3][1], 0, 0, 0);
        }

        // ---- epilogue: logits ARE acc (norms+S baked) -> online (M,S) ----
#pragma unroll
        for (int mf = 0; mf < 4; ++mf)
#pragma unroll
            for (int i = 0; i < 4; ++i) {
                float v0 = acc[mf][0][i];
                float v1 = acc[mf][1][i];
                float pm = fmaxf(v0, v1);
                float nM = fmaxf(Mr[mf][i], pm);
                Sr[mf][i] = Sr[mf][i] * __expf(Mr[mf][i] - nM)
                          + __expf(v0 - nM) + __expf(v1 - nM);
                Mr[mf][i] = nM;
            }

        __builtin_amdgcn_sched_barrier(0);
        __builtin_amdgcn_s_barrier();      // all waves done reading Bl[buf]
        __builtin_amdgcn_sched_barrier(0);
        buf ^= 1;
    }

    // ---- merge across the 16 column-lanes, one write per row ----
#pragma unroll
    for (int mf = 0; mf < 4; ++mf)
#pragma unroll
        for (int i = 0; i < 4; ++i) {
            float M = Mr[mf][i], S = Sr[mf][i];
#pragma unroll
            for (int d = 1; d < 16; d <<= 1) {
                float oM = __shfl_xor(M, d), oS = __shfl_xor(S, d);
                float nM = fmaxf(M, oM);
                S = S * __expf(M - nM) + oS * __expf(oM - nM);
                M = nM;
            }
            if (l15 == 0) {
                int m = wv * 64 + mf * 16 + lg * 4 + i;
                pms[(size_t)blockIdx.x * BATCH + m] = make_float2(M, S);
            }
        }
}

// ---------------------------------------------------------------------------
// k_mainS: fallback (round-7 kernel) if ws can't hold Wb.
// ---------------------------------------------------------------------------
__global__ __launch_bounds__(1024, 4) void k_mainS(
        const float* __restrict__ W, const unsigned short* __restrict__ xb,
        float2* __restrict__ pms) {
    __shared__ __align__(16) char B32[BN * EMB * 4];
    __shared__ float ssq[BN];

    const int tid  = threadIdx.x;
    const int lane = tid & 63;
    const int wv   = tid >> 6;
    const int l15  = lane & 15;
    const int lg   = lane >> 4;
    const int sw   = (l15 & 7) << 4;
    const unsigned short* xp = xb + (size_t)(wv * 32 + l15) * EMB;

    float Mr[2][4], Sr[2][4];
#pragma unroll
    for (int mf = 0; mf < 2; ++mf)
#pragma unroll
        for (int i = 0; i < 4; ++i) { Mr[mf][i] = -1e38f; Sr[mf][i] = 0.0f; }

    auto issue4 = [&](int ci, int qb) {
#pragma unroll
        for (int q = qb; q < qb + 4; ++q) {
            int unit = q * 1024 + tid;
            int c    = ci * BN + (unit >> 7);
            if (c > NUM_CLASSES - 1) c = NUM_CLASSES - 1;
            const char* src = (const char*)W + (size_t)c * (EMB * 4)
                            + (unit & 127) * 16;
            __builtin_amdgcn_global_load_lds(
                (const __attribute__((address_space(1))) unsigned int*)src,
                (__attribute__((address_space(3))) unsigned int*)
                    (B32 + q * 16384 + wv * 1024),
                16, 0, 0);
        }
    };

    issue4(blockIdx.x, 0);
    issue4(blockIdx.x, 4);

    for (int ci = blockIdx.x; ci < NBLK; ci += GRID_S) {
        asm volatile("s_waitcnt vmcnt(0)" ::: "memory");
        __builtin_amdgcn_sched_barrier(0);
        __builtin_amdgcn_s_barrier();

        if (tid < BN) ssq[tid] = 0.0f;

        const float4* Bf = (const float4*)B32;
        float4 r[8];
#pragma unroll
        for (int q = 0; q < 8; ++q) r[q] = Bf[q * 1024 + tid];
        float sq[8];
#pragma unroll
        for (int q = 0; q < 8; ++q)
            sq[q] = r[q].x*r[q].x + r[q].y*r[q].y + r[q].z*r[q].z + r[q].w*r[q].w;

        asm volatile("s_waitcnt lgkmcnt(0)" ::: "memory");
        __builtin_amdgcn_sched_barrier(0);
        __builtin_amdgcn_s_barrier();

        const bool has = (ci + GRID_S) < NBLK;
        if (has) issue4(ci + GRID_S, 4);

        const int kb = (tid & 127) * 8;
#pragma unroll
        for (int q = 0; q < 8; ++q) {
            int cls = q * 8 + (tid >> 7);
            unsigned lo, hi;
            asm("v_cvt_pk_bf16_f32 %0, %1, %2" : "=v"(lo) : "v"(r[q].x), "v"(r[q].y));
            asm("v_cvt_pk_bf16_f32 %0, %1, %2" : "=v"(hi) : "v"(r[q].z), "v"(r[q].w));
            *(uint2*)(B32 + cls * 1024 + (kb ^ ((cls & 7) << 4))) = make_uint2(lo, hi);
        }
#pragma unroll
        for (int q = 0; q < 8; ++q) {
            float s = sq[q];
            s += __shfl_xor(s, 1);  s += __shfl_xor(s, 2);  s += __shfl_xor(s, 4);
            s += __shfl_xor(s, 8);  s += __shfl_xor(s, 16); s += __shfl_xor(s, 32);
            if (lane == 0) atomicAdd(&ssq[q * 8 + (tid >> 7)], s);
        }

        asm volatile("s_waitcnt lgkmcnt(0)" ::: "memory");
        __builtin_amdgcn_sched_barrier(0);
        __builtin_amdgcn_s_barrier();

        f4 acc[2][4];
#pragma unroll
        for (int mf = 0; mf < 2; ++mf)
#pragma unroll
            for (int nf = 0; nf < 4; ++nf)
#pragma unroll
                for (int i = 0; i < 4; ++i) acc[mf][nf][i] = 0.0f;

#pragma unroll 4
        for (int k0 = 0; k0 < EMB; k0 += 32) {
            int kb2 = k0 * 2 + lg * 16;
            bf8 b0 = *(const bf8*)(B32 + (0 * 16 + l15) * 1024 + (kb2 ^ sw));
            bf8 b1 = *(const bf8*)(B32 + (1 * 16 + l15) * 1024 + (kb2 ^ sw));
            bf8 b2 = *(const bf8*)(B32 + (2 * 16 + l15) * 1024 + (kb2 ^ sw));
            bf8 b3 = *(const bf8*)(B32 + (3 * 16 + l15) * 1024 + (kb2 ^ sw));
            bf8 a0 = *(const bf8*)(xp + k0 + lg * 8);
            bf8 a1 = *(const bf8*)(xp + 16 * EMB + k0 + lg * 8);
            acc[0][0] = __builtin_amdgcn_mfma_f32_16x16x32_bf16(a0, b0, acc[0][0], 0, 0, 0);
            acc[0][1] = __builtin_amdgcn_mfma_f32_16x16x32_bf16(a0, b1, acc[0][1], 0, 0, 0);
            acc[0][2] = __builtin_amdgcn_mfma_f32_16x16x32_bf16(a0, b2, acc[0][2], 0, 0, 0);
            acc[0][3] = __builtin_amdgcn_mfma_f32_16x16x32_bf16(a0, b3, acc[0][3], 0, 0, 0);
            acc[1][0] = __builtin_amdgcn_mfma_f32_16x16x32_bf16(a1, b0, acc[1][0], 0, 0, 0);
            acc[1][1] = __builtin_amdgcn_mfma_f32_16x16x32_bf16(a1, b1, acc[1][1], 0, 0, 0);
            acc[1][2] = __builtin_amdgcn_mfma_f32_16x16x32_bf16(a1, b2, acc[1][2], 0, 0, 0);
            acc[1][3] = __builtin_amdgcn_mfma_f32_16x16x32_bf16(a1, b3, acc[1][3], 0, 0, 0);
        }

        float rn[4];
#pragma unroll
        for (int nf = 0; nf < 4; ++nf)
            rn[nf] = S_SCALE / fmaxf(sqrtf(ssq[nf * 16 + l15]), 1e-12f);
        const int  c0   = ci * BN;
        const bool tail = (c0 + BN > NUM_CLASSES);
#pragma unroll
        for (int mf = 0; mf < 2; ++mf)
#pragma unroll
            for (int i = 0; i < 4; ++i) {
                float v0 = acc[mf][0][i] * rn[0];
                float v1 = acc[mf][1][i] * rn[1];
                float v2 = acc[mf][2][i] * rn[2];
                float v3 = acc[mf][3][i] * rn[3];
                if (tail) {
                    if (c0 + 0 * 16 + l15 >= NUM_CLASSES) v0 = -1e30f;
                    if (c0 + 1 * 16 + l15 >= NUM_CLASSES) v1 = -1e30f;
                    if (c0 + 2 * 16 + l15 >= NUM_CLASSES) v2 = -1e30f;
                    if (c0 + 3 * 16 + l15 >= NUM_CLASSES) v3 = -1e30f;
                }
                float pm = fmaxf(fmaxf(v0, v1), fmaxf(v2, v3));
                float nM = fmaxf(Mr[mf][i], pm);
                Sr[mf][i] = Sr[mf][i] * __expf(Mr[mf][i] - nM)
                          + __expf(v0 - nM) + __expf(v1 - nM)
                          + __expf(v2 - nM) + __expf(v3 - nM);
                Mr[mf][i] = nM;
            }

        __builtin_amdgcn_sched_barrier(0);
        __builtin_amdgcn_s_barrier();
        if (has) issue4(ci + GRID_S, 0);
    }

#pragma unroll
    for (int mf = 0; mf < 2; ++mf)
#pragma unroll
        for (int i = 0; i < 4; ++i) {
            float M = Mr[mf][i], S = Sr[mf][i];
#pragma unroll
            for (int d = 1; d < 16; d <<= 1) {
                float oM = __shfl_xor(M, d), oS = __shfl_xor(S, d);
                float nM = fmaxf(M, oM);
                S = S * __expf(M - nM) + oS * __expf(oM - nM);
                M = nM;
            }
            if (l15 == 0) {
                int m = wv * 32 + mf * 16 + lg * 4 + i;
                pms[(size_t)blockIdx.x * BATCH + m] = make_float2(M, S);
            }
        }
}

// ---------------------------------------------------------------------------
// k_red: merge Q block-partials per reduction slot, coalesced.
// ---------------------------------------------------------------------------
__global__ __launch_bounds__(512) void k_red(const float2* __restrict__ pms,
                                             float2* __restrict__ part, int Q) {
    int t = threadIdx.x, b = blockIdx.x;
    float M = -1e38f, S = 0.f;
    for (int q = 0; q < Q; ++q) {
        float2 v = pms[(size_t)(b * Q + q) * BATCH + t];
        float nM = fmaxf(M, v.x);
        S = S * __expf(M - nM) + v.y * __expf(v.x - nM);
        M = nM;
    }
    part[b * BATCH + t] = make_float2(M, S);
}

// ---------------------------------------------------------------------------
// k_fin: merge 64 partials per row, patch label col (plain->margin), mean.
// ---------------------------------------------------------------------------
__global__ __launch_bounds__(512) void k_fin(const float2* __restrict__ part,
                                             const float* __restrict__ tcos,
                                             const float* __restrict__ tphi,
                                             float* __restrict__ out) {
    int t = threadIdx.x;
    float M = -1e38f, S = 0.f;
    for (int b = 0; b < RBLK; ++b) {
        float2 v = part[b * BATCH + t];
        float nM = fmaxf(M, v.x);
        S = S * __expf(M - nM) + v.y * __expf(v.x - nM);
        M = nM;
    }
    float Sc = S - __expf(tcos[t] - M) + __expf(tphi[t] - M);
    Sc = fmaxf(Sc, 1e-30f);
    float loss = M + logf(Sc) - tphi[t];
#pragma unroll
    for (int d = 1; d < 64; d <<= 1) loss += __shfl_xor(loss, d);
    __shared__ float wred[8];
    if ((t & 63) == 0) wred[t >> 6] = loss;
    __syncthreads();
    if (t == 0) {
        float s = 0.f;
        for (int w = 0; w < 8; ++w) s += wred[w];
        out[0] = s / (float)BATCH;
    }
}

extern "C" void kernel_launch(void* const* d_in, const int* in_sizes, int n_in,
                              void* d_out, int out_size, void* d_ws, size_t ws_size,
                              hipStream_t stream) {
    const float*     x     = (const float*)d_in[0];
    const long long* label = (const long long*)d_in[1];
    const float*     W     = (const float*)d_in[2];
    float*           out   = (float*)d_out;

    // workspace layout
    char* ws = (char*)d_ws;
    unsigned short* xb   = (unsigned short*)ws;              // 524288
    float*          tcos = (float*)(ws + 524288);            // 2048
    float*          tphi = (float*)(ws + 526336);            // 2048
    float2*         pms  = (float2*)(ws + 528384);           // 512*512*8 = 2097152
    float2*         part = (float2*)(ws + 2625536);          // 64*512*8 = 262144
    unsigned short* Wb   = (unsigned short*)(ws + 2887680);  // 100000*1024 B
    const size_t WS_NEED = 2887680ull + (size_t)NUM_CLASSES * 1024;

    k_normx<<<BATCH / 4, 256, 0, stream>>>(x, xb);
    k_tgt  <<<BATCH / 8, 512, 0, stream>>>(x, W, label, tcos, tphi);
    if (ws_size >= WS_NEED) {
        k_prep <<<NUM_CLASSES / 4, 256, 0, stream>>>(W, Wb);
        k_mainF<<<GRID_F, 512,  0, stream>>>(Wb, xb, pms);
        k_red  <<<RBLK,   512,  0, stream>>>(pms, part, GRID_F / RBLK);
    } else {
        k_mainS<<<GRID_S, 1024, 0, stream>>>(W, xb, pms);
        k_red  <<<RBLK,   512,  0, stream>>>(pms, part, GRID_S / RBLK);
    }
    k_fin<<<1, 512, 0, stream>>>(part, tcos, tphi, out);
}

// Round 9
// 130.767 us; speedup vs baseline: 1.9993x; 1.9993x over previous
//
#include <hip/hip_runtime.h>
#include <math.h>

#define NUM_CLASSES 100000
#define EMB 512
#define BATCH 512

/* fast path */
#define BNF 32                        /* classes per chunk */
#define NCHUNK (NUM_CLASSES / BNF)    /* 3125, exact — no tail */
#define NBC 128                       /* chunk columns */
#define NRG 4                         /* row groups of 128 rows */
#define GRID_F (NBC * NRG)            /* 512 blocks, 2/CU */
/* fallback path */
#define BN 64
#define NBLK ((NUM_CLASSES + BN - 1) / BN)
#define GRID_S 256

#define RBLK 64

// ArcFace constants (margin m=0.3, scale s=120)
#define S_SCALE 120.0f
#define COS_M   0.9553364891256061f
#define SIN_M   0.29552020666133955f
#define TH_C   (-0.9553364891256061f)
#define MM_C    0.08865606199840187f

typedef short bf8 __attribute__((ext_vector_type(8)));   // 8 x bf16
typedef float f4  __attribute__((ext_vector_type(4)));   // MFMA accumulator

__device__ __forceinline__ unsigned short f2bf(float f) {
    union { float f; unsigned u; } a; a.f = f;
    unsigned r = a.u + 0x7fffu + ((a.u >> 16) & 1u);
    return (unsigned short)(r >> 16);
}

// ---------------------------------------------------------------------------
// k_normx: L2-normalize rows of x (f32) -> bf16, one wave per row.
// ---------------------------------------------------------------------------
__global__ __launch_bounds__(256) void k_normx(const float* __restrict__ x,
                                               unsigned short* __restrict__ xb) {
    int row  = blockIdx.x * 4 + (threadIdx.x >> 6);
    int lane = threadIdx.x & 63;
    const float4* xr = (const float4*)(x + (size_t)row * EMB);
    float4 a = xr[lane * 2];
    float4 b = xr[lane * 2 + 1];
    float ss = a.x*a.x + a.y*a.y + a.z*a.z + a.w*a.w
             + b.x*b.x + b.y*b.y + b.z*b.z + b.w*b.w;
#pragma unroll
    for (int d = 1; d < 64; d <<= 1) ss += __shfl_xor(ss, d);
    float rn = 1.0f / fmaxf(sqrtf(ss), 1e-12f);
    int4 o;
    o.x = f2bf(a.x * rn) | (f2bf(a.y * rn) << 16);
    o.y = f2bf(a.z * rn) | (f2bf(a.w * rn) << 16);
    o.z = f2bf(b.x * rn) | (f2bf(b.y * rn) << 16);
    o.w = f2bf(b.z * rn) | (f2bf(b.w * rn) << 16);
    ((int4*)(xb + (size_t)row * EMB))[lane] = o;
}

// ---------------------------------------------------------------------------
// k_tgt: exact f32 target logit per row: s*cos and s*phi at the label.
// ---------------------------------------------------------------------------
__global__ __launch_bounds__(512) void k_tgt(const float* __restrict__ x,
                                             const float* __restrict__ W,
                                             const long long* __restrict__ label,
                                             float* __restrict__ tcos,
                                             float* __restrict__ tphi) {
    int m    = blockIdx.x * 8 + (threadIdx.x >> 6);
    int lane = threadIdx.x & 63;
    int lb   = (int)label[m];
    const float4* xr = (const float4*)(x + (size_t)m  * EMB);
    const float4* wr = (const float4*)(W + (size_t)lb * EMB);
    float sx = 0.f, sw = 0.f, sd = 0.f;
#pragma unroll
    for (int q = 0; q < 2; ++q) {
        float4 a = xr[lane * 2 + q];
        float4 b = wr[lane * 2 + q];
        sx += a.x*a.x + a.y*a.y + a.z*a.z + a.w*a.w;
        sw += b.x*b.x + b.y*b.y + b.z*b.z + b.w*b.w;
        sd += a.x*b.x + a.y*b.y + a.z*b.z + a.w*b.w;
    }
#pragma unroll
    for (int d = 1; d < 64; d <<= 1) {
        sx += __shfl_xor(sx, d);
        sw += __shfl_xor(sw, d);
        sd += __shfl_xor(sd, d);
    }
    if (lane == 0) {
        float cv = sd / (fmaxf(sqrtf(sx), 1e-12f) * fmaxf(sqrtf(sw), 1e-12f));
        float sine = sqrtf(fmaxf(0.f, 1.f - cv * cv));
        float phi  = cv * COS_M - sine * SIN_M;
        if (!(cv > TH_C)) phi = cv - MM_C;
        tcos[m] = S_SCALE * cv;
        tphi[m] = S_SCALE * phi;
    }
}

// ---------------------------------------------------------------------------
// k_prep: W f32 -> Wb bf16 with S/||w|| folded in, PRE-SWIZZLED so k_mainF's
// staging is a linear memcpy-to-LDS and its swizzled ds_reads see the right
// bytes. One wave per class. (Verified correct in round 8.)
// ---------------------------------------------------------------------------
__global__ __launch_bounds__(256) void k_prep(const float* __restrict__ W,
                                              unsigned short* __restrict__ Wb) {
    int w    = blockIdx.x * 4 + (threadIdx.x >> 6);
    int lane = threadIdx.x & 63;
    const float4* r = (const float4*)(W + (size_t)w * EMB);
    float4 a = r[lane * 2];
    float4 b = r[lane * 2 + 1];
    float ss = a.x*a.x + a.y*a.y + a.z*a.z + a.w*a.w
             + b.x*b.x + b.y*b.y + b.z*b.z + b.w*b.w;
#pragma unroll
    for (int d = 1; d < 64; d <<= 1) ss += __shfl_xor(ss, d);
    float rn = S_SCALE / fmaxf(sqrtf(ss), 1e-12f);
    uint4 o;
    o.x = f2bf(a.x*rn) | (f2bf(a.y*rn) << 16);
    o.y = f2bf(a.z*rn) | (f2bf(a.w*rn) << 16);
    o.z = f2bf(b.x*rn) | (f2bf(b.y*rn) << 16);
    o.w = f2bf(b.z*rn) | (f2bf(b.w*rn) << 16);
    *(uint4*)((char*)Wb + (size_t)w * 1024 + ((unsigned)(lane ^ (w & 7)) << 4)) = o;
}

// ---------------------------------------------------------------------------
// k_mainF: A-in-registers streaming GEMM + per-lane online LSE.
// Grid = 4 row-groups x 128 chunk-columns (512 blocks, 512 thr, 2/CU).
// Wave = 16 rows x 32 classes; A (16 rows x 512 k) lives in 16 bf8 regs,
// loaded ONCE from xb. k-loop is pure LDS+MFMA: 16 x (2 swizzled
// ds_read_b128 + 2 MFMA). B staged via 4 global_load_lds/wave, counted
// vmcnt(4), raw barriers (prefetch stays in flight). Blocks sharing a
// chunk-column stride land on the same XCD ((rg*128+bc)%8 == bc%8) so the
// 4x B re-read is L2-resident.
// ---------------------------------------------------------------------------
__global__ __launch_bounds__(512, 4) void k_mainF(
        const unsigned short* __restrict__ Wb,
        const unsigned short* __restrict__ xb,
        float2* __restrict__ pms) {
    __shared__ __align__(16) unsigned short Bl[2][BNF * EMB];  // 2 x 32 KiB

    const int tid  = threadIdx.x;
    const int lane = tid & 63;
    const int wv   = tid >> 6;           // wave 0..7
    const int l15  = lane & 15;
    const int lg   = lane >> 4;
    const int bc   = blockIdx.x & (NBC - 1);   // chunk column
    const int rg   = blockIdx.x >> 7;          // row group

    // ---- A into registers: rows rg*128 + wv*16 .. +16, all K ----
    const unsigned short* xp = xb + (size_t)(rg * 128 + wv * 16 + l15) * EMB;
    bf8 a[16];
#pragma unroll
    for (int ks = 0; ks < 16; ++ks)
        a[ks] = *(const bf8*)(xp + ks * 32 + lg * 8);

    // per-lane online-softmax state: 4 row-slots x this lane's 2 columns
    float Mr[4], Sr[4];
#pragma unroll
    for (int i = 0; i < 4; ++i) { Mr[i] = -1e38f; Sr[i] = 0.0f; }

    const char* WbB = (const char*)Wb;
    auto issue = [&](int ci, int b) {
        const char* src = WbB + (size_t)ci * (BNF * EMB * 2) + wv * 4096 + lane * 16;
        char* dst = (char*)&Bl[b][0] + wv * 4096;   // wave-uniform base
#pragma unroll
        for (int r2 = 0; r2 < 4; ++r2)
            __builtin_amdgcn_global_load_lds(
                (const __attribute__((address_space(1))) unsigned int*)(src + r2 * 1024),
                (__attribute__((address_space(3))) unsigned int*)(dst + r2 * 1024),
                16, 0, 0);
    };

    issue(bc, 0);
    int buf = 0;
    for (int ci = bc; ci < NCHUNK; ci += NBC) {
        int cn = ci + NBC;
        if (cn < NCHUNK) {
            issue(cn, buf ^ 1);
            asm volatile("s_waitcnt vmcnt(4)" ::: "memory");   // current buf ready
        } else {
            asm volatile("s_waitcnt vmcnt(0)" ::: "memory");
        }
        __builtin_amdgcn_sched_barrier(0);
        __builtin_amdgcn_s_barrier();
        __builtin_amdgcn_sched_barrier(0);

        // ---- pure LDS+MFMA k-loop: 16 rows x 32 classes ----
        f4 acc0, acc1;
#pragma unroll
        for (int i = 0; i < 4; ++i) { acc0[i] = 0.0f; acc1[i] = 0.0f; }

        const char* BB = (const char*)&Bl[buf][0];
#pragma unroll
        for (int ks = 0; ks < 16; ++ks) {
            int u  = ks * 4 + lg;                     // 16B unit in row
            int sx = ((u ^ (l15 & 7)) << 4);          // swizzled byte offset
            bf8 b0 = *(const bf8*)(BB + l15 * 1024 + sx);
            bf8 b1 = *(const bf8*)(BB + (16 + l15) * 1024 + sx);
            acc0 = __builtin_amdgcn_mfma_f32_16x16x32_bf16(a[ks], b0, acc0, 0, 0, 0);
            acc1 = __builtin_amdgcn_mfma_f32_16x16x32_bf16(a[ks], b1, acc1, 0, 0, 0);
        }

        // ---- epilogue: logits ARE acc (S/||w|| baked) -> online (M,S) ----
#pragma unroll
        for (int i = 0; i < 4; ++i) {
            float v0 = acc0[i];
            float v1 = acc1[i];
            float pm = fmaxf(v0, v1);
            float nM = fmaxf(Mr[i], pm);
            Sr[i] = Sr[i] * __expf(Mr[i] - nM)
                  + __expf(v0 - nM) + __expf(v1 - nM);
            Mr[i] = nM;
        }

        __builtin_amdgcn_sched_barrier(0);
        __builtin_amdgcn_s_barrier();       // all waves done reading Bl[buf]
        __builtin_amdgcn_sched_barrier(0);
        buf ^= 1;
    }

    // ---- merge (M,S) across the 16 column-lanes, one write per row ----
#pragma unroll
    for (int i = 0; i < 4; ++i) {
        float M = Mr[i], S = Sr[i];
#pragma unroll
        for (int d = 1; d < 16; d <<= 1) {
            float oM = __shfl_xor(M, d), oS = __shfl_xor(S, d);
            float nM = fmaxf(M, oM);
            S = S * __expf(M - nM) + oS * __expf(oM - nM);
            M = nM;
        }
        if (l15 == 0) {
            int m = rg * 128 + wv * 16 + lg * 4 + i;
            pms[(size_t)bc * BATCH + m] = make_float2(M, S);
        }
    }
}

// ---------------------------------------------------------------------------
// k_mainS: fallback (round-7 structure) if ws can't hold Wb.
// ---------------------------------------------------------------------------
__global__ __launch_bounds__(1024, 4) void k_mainS(
        const float* __restrict__ W, const unsigned short* __restrict__ xb,
        float2* __restrict__ pms) {
    __shared__ __align__(16) char B32[BN * EMB * 4];
    __shared__ float ssq[BN];

    const int tid  = threadIdx.x;
    const int lane = tid & 63;
    const int wv   = tid >> 6;
    const int l15  = lane & 15;
    const int lg   = lane >> 4;
    const int sw   = (l15 & 7) << 4;
    const unsigned short* xp = xb + (size_t)(wv * 32 + l15) * EMB;

    float Mr[2][4], Sr[2][4];
#pragma unroll
    for (int mf = 0; mf < 2; ++mf)
#pragma unroll
        for (int i = 0; i < 4; ++i) { Mr[mf][i] = -1e38f; Sr[mf][i] = 0.0f; }

    auto issue4 = [&](int ci, int qb) {
#pragma unroll
        for (int q = qb; q < qb + 4; ++q) {
            int unit = q * 1024 + tid;
            int c    = ci * BN + (unit >> 7);
            if (c > NUM_CLASSES - 1) c = NUM_CLASSES - 1;
            const char* src = (const char*)W + (size_t)c * (EMB * 4)
                            + (unit & 127) * 16;
            __builtin_amdgcn_global_load_lds(
                (const __attribute__((address_space(1))) unsigned int*)src,
                (__attribute__((address_space(3))) unsigned int*)
                    (B32 + q * 16384 + wv * 1024),
                16, 0, 0);
        }
    };

    issue4(blockIdx.x, 0);
    issue4(blockIdx.x, 4);

    for (int ci = blockIdx.x; ci < NBLK; ci += GRID_S) {
        asm volatile("s_waitcnt vmcnt(0)" ::: "memory");
        __builtin_amdgcn_sched_barrier(0);
        __builtin_amdgcn_s_barrier();

        if (tid < BN) ssq[tid] = 0.0f;

        const float4* Bf = (const float4*)B32;
        float4 r[8];
#pragma unroll
        for (int q = 0; q < 8; ++q) r[q] = Bf[q * 1024 + tid];
        float sq[8];
#pragma unroll
        for (int q = 0; q < 8; ++q)
            sq[q] = r[q].x*r[q].x + r[q].y*r[q].y + r[q].z*r[q].z + r[q].w*r[q].w;

        asm volatile("s_waitcnt lgkmcnt(0)" ::: "memory");
        __builtin_amdgcn_sched_barrier(0);
        __builtin_amdgcn_s_barrier();

        const bool has = (ci + GRID_S) < NBLK;
        if (has) issue4(ci + GRID_S, 4);

        const int kb = (tid & 127) * 8;
#pragma unroll
        for (int q = 0; q < 8; ++q) {
            int cls = q * 8 + (tid >> 7);
            unsigned lo, hi;
            asm("v_cvt_pk_bf16_f32 %0, %1, %2" : "=v"(lo) : "v"(r[q].x), "v"(r[q].y));
            asm("v_cvt_pk_bf16_f32 %0, %1, %2" : "=v"(hi) : "v"(r[q].z), "v"(r[q].w));
            *(uint2*)(B32 + cls * 1024 + (kb ^ ((cls & 7) << 4))) = make_uint2(lo, hi);
        }
#pragma unroll
        for (int q = 0; q < 8; ++q) {
            float s = sq[q];
            s += __shfl_xor(s, 1);  s += __shfl_xor(s, 2);  s += __shfl_xor(s, 4);
            s += __shfl_xor(s, 8);  s += __shfl_xor(s, 16); s += __shfl_xor(s, 32);
            if (lane == 0) atomicAdd(&ssq[q * 8 + (tid >> 7)], s);
        }

        asm volatile("s_waitcnt lgkmcnt(0)" ::: "memory");
        __builtin_amdgcn_sched_barrier(0);
        __builtin_amdgcn_s_barrier();

        f4 acc[2][4];
#pragma unroll
        for (int mf = 0; mf < 2; ++mf)
#pragma unroll
            for (int nf = 0; nf < 4; ++nf)
#pragma unroll
                for (int i = 0; i < 4; ++i) acc[mf][nf][i] = 0.0f;

#pragma unroll 4
        for (int k0 = 0; k0 < EMB; k0 += 32) {
            int kb2 = k0 * 2 + lg * 16;
            bf8 b0 = *(const bf8*)(B32 + (0 * 16 + l15) * 1024 + (kb2 ^ sw));
            bf8 b1 = *(const bf8*)(B32 + (1 * 16 + l15) * 1024 + (kb2 ^ sw));
            bf8 b2 = *(const bf8*)(B32 + (2 * 16 + l15) * 1024 + (kb2 ^ sw));
            bf8 b3 = *(const bf8*)(B32 + (3 * 16 + l15) * 1024 + (kb2 ^ sw));
            bf8 a0 = *(const bf8*)(xp + k0 + lg * 8);
            bf8 a1 = *(const bf8*)(xp + 16 * EMB + k0 + lg * 8);
            acc[0][0] = __builtin_amdgcn_mfma_f32_16x16x32_bf16(a0, b0, acc[0][0], 0, 0, 0);
            acc[0][1] = __builtin_amdgcn_mfma_f32_16x16x32_bf16(a0, b1, acc[0][1], 0, 0, 0);
            acc[0][2] = __builtin_amdgcn_mfma_f32_16x16x32_bf16(a0, b2, acc[0][2], 0, 0, 0);
            acc[0][3] = __builtin_amdgcn_mfma_f32_16x16x32_bf16(a0, b3, acc[0][3], 0, 0, 0);
            acc[1][0] = __builtin_amdgcn_mfma_f32_16x16x32_bf16(a1, b0, acc[1][0], 0, 0, 0);
            acc[1][1] = __builtin_amdgcn_mfma_f32_16x16x32_bf16(a1, b1, acc[1][1], 0, 0, 0);
            acc[1][2] = __builtin_amdgcn_mfma_f32_16x16x32_bf16(a1, b2, acc[1][2], 0, 0, 0);
            acc[1][3] = __builtin_amdgcn_mfma_f32_16x16x32_bf16(a1, b3, acc[1][3], 0, 0, 0);
        }

        float rn[4];
#pragma unroll
        for (int nf = 0; nf < 4; ++nf)
            rn[nf] = S_SCALE / fmaxf(sqrtf(ssq[nf * 16 + l15]), 1e-12f);
        const int  c0   = ci * BN;
        const bool tail = (c0 + BN > NUM_CLASSES);
#pragma unroll
        for (int mf = 0; mf < 2; ++mf)
#pragma unroll
            for (int i = 0; i < 4; ++i) {
                float v0 = acc[mf][0][i] * rn[0];
                float v1 = acc[mf][1][i] * rn[1];
                float v2 = acc[mf][2][i] * rn[2];
                float v3 = acc[mf][3][i] * rn[3];
                if (tail) {
                    if (c0 + 0 * 16 + l15 >= NUM_CLASSES) v0 = -1e30f;
                    if (c0 + 1 * 16 + l15 >= NUM_CLASSES) v1 = -1e30f;
                    if (c0 + 2 * 16 + l15 >= NUM_CLASSES) v2 = -1e30f;
                    if (c0 + 3 * 16 + l15 >= NUM_CLASSES) v3 = -1e30f;
                }
                float pm = fmaxf(fmaxf(v0, v1), fmaxf(v2, v3));
                float nM = fmaxf(Mr[mf][i], pm);
                Sr[mf][i] = Sr[mf][i] * __expf(Mr[mf][i] - nM)
                          + __expf(v0 - nM) + __expf(v1 - nM)
                          + __expf(v2 - nM) + __expf(v3 - nM);
                Mr[mf][i] = nM;
            }

        __builtin_amdgcn_sched_barrier(0);
        __builtin_amdgcn_s_barrier();
        if (has) issue4(ci + GRID_S, 0);
    }

#pragma unroll
    for (int mf = 0; mf < 2; ++mf)
#pragma unroll
        for (int i = 0; i < 4; ++i) {
            float M = Mr[mf][i], S = Sr[mf][i];
#pragma unroll
            for (int d = 1; d < 16; d <<= 1) {
                float oM = __shfl_xor(M, d), oS = __shfl_xor(S, d);
                float nM = fmaxf(M, oM);
                S = S * __expf(M - nM) + oS * __expf(oM - nM);
                M = nM;
            }
            if (l15 == 0) {
                int m = wv * 32 + mf * 16 + lg * 4 + i;
                pms[(size_t)blockIdx.x * BATCH + m] = make_float2(M, S);
            }
        }
}

// ---------------------------------------------------------------------------
// k_red: merge Q column-partials per reduction slot, coalesced.
// ---------------------------------------------------------------------------
__global__ __launch_bounds__(512) void k_red(const float2* __restrict__ pms,
                                             float2* __restrict__ part, int Q) {
    int t = threadIdx.x, b = blockIdx.x;
    float M = -1e38f, S = 0.f;
    for (int q = 0; q < Q; ++q) {
        float2 v = pms[(size_t)(b * Q + q) * BATCH + t];
        float nM = fmaxf(M, v.x);
        S = S * __expf(M - nM) + v.y * __expf(v.x - nM);
        M = nM;
    }
    part[b * BATCH + t] = make_float2(M, S);
}

// ---------------------------------------------------------------------------
// k_fin: merge 64 partials per row, patch label col (plain->margin), mean.
// ---------------------------------------------------------------------------
__global__ __launch_bounds__(512) void k_fin(const float2* __restrict__ part,
                                             const float* __restrict__ tcos,
                                             const float* __restrict__ tphi,
                                             float* __restrict__ out) {
    int t = threadIdx.x;
    float M = -1e38f, S = 0.f;
    for (int b = 0; b < RBLK; ++b) {
        float2 v = part[b * BATCH + t];
        float nM = fmaxf(M, v.x);
        S = S * __expf(M - nM) + v.y * __expf(v.x - nM);
        M = nM;
    }
    float Sc = S - __expf(tcos[t] - M) + __expf(tphi[t] - M);
    Sc = fmaxf(Sc, 1e-30f);
    float loss = M + logf(Sc) - tphi[t];
#pragma unroll
    for (int d = 1; d < 64; d <<= 1) loss += __shfl_xor(loss, d);
    __shared__ float wred[8];
    if ((t & 63) == 0) wred[t >> 6] = loss;
    __syncthreads();
    if (t == 0) {
        float s = 0.f;
        for (int w = 0; w < 8; ++w) s += wred[w];
        out[0] = s / (float)BATCH;
    }
}

extern "C" void kernel_launch(void* const* d_in, const int* in_sizes, int n_in,
                              void* d_out, int out_size, void* d_ws, size_t ws_size,
                              hipStream_t stream) {
    const float*     x     = (const float*)d_in[0];
    const long long* label = (const long long*)d_in[1];
    const float*     W     = (const float*)d_in[2];
    float*           out   = (float*)d_out;

    // workspace layout
    char* ws = (char*)d_ws;
    unsigned short* xb   = (unsigned short*)ws;              // 524288
    float*          tcos = (float*)(ws + 524288);            // 2048
    float*          tphi = (float*)(ws + 526336);            // 2048
    float2*         pms  = (float2*)(ws + 528384);           // 1048576 (max path)
    float2*         part = (float2*)(ws + 1576960);          // 262144
    unsigned short* Wb   = (unsigned short*)(ws + 1839104);  // 100000*1024 B
    const size_t WS_NEED = 1839104ull + (size_t)NUM_CLASSES * 1024;

    k_normx<<<BATCH / 4, 256, 0, stream>>>(x, xb);
    k_tgt  <<<BATCH / 8, 512, 0, stream>>>(x, W, label, tcos, tphi);
    if (ws_size >= WS_NEED) {
        k_prep <<<NUM_CLASSES / 4, 256, 0, stream>>>(W, Wb);
        k_mainF<<<GRID_F, 512,  0, stream>>>(Wb, xb, pms);
        k_red  <<<RBLK,   512,  0, stream>>>(pms, part, NBC / RBLK);
    } else {
        k_mainS<<<GRID_S, 1024, 0, stream>>>(W, xb, pms);
        k_red  <<<RBLK,   512,  0, stream>>>(pms, part, GRID_S / RBLK);
    }
    k_fin<<<1, 512, 0, stream>>>(part, tcos, tphi, out);
}

// Round 10
// 122.915 us; speedup vs baseline: 2.1270x; 1.0639x over previous
//
#include <hip/hip_runtime.h>
#include <math.h>

#define NUM_CLASSES 100000
#define EMB 512
#define BATCH 512

/* fast path */
#define BNF 32                        /* classes per chunk */
#define NCHUNK (NUM_CLASSES / BNF)    /* 3125, exact — no tail */
#define NBC 128                       /* chunk columns */
#define NRG 2                         /* row groups of 256 rows */
#define GRID_F (NBC * NRG)            /* 256 blocks, 1/CU */
/* fallback path */
#define BN 64
#define NBLK ((NUM_CLASSES + BN - 1) / BN)
#define GRID_S 256

#define RBLK 64

// ArcFace constants (margin m=0.3, scale s=120)
#define S_SCALE 120.0f
#define COS_M   0.9553364891256061f
#define SIN_M   0.29552020666133955f
#define TH_C   (-0.9553364891256061f)
#define MM_C    0.08865606199840187f

typedef short bf8 __attribute__((ext_vector_type(8)));   // 8 x bf16
typedef float f4  __attribute__((ext_vector_type(4)));   // MFMA accumulator
typedef float f32x4 __attribute__((ext_vector_type(4)));

__device__ __forceinline__ unsigned short f2bf(float f) {
    union { float f; unsigned u; } a; a.f = f;
    unsigned r = a.u + 0x7fffu + ((a.u >> 16) & 1u);
    return (unsigned short)(r >> 16);
}

// ---------------------------------------------------------------------------
// k_normx: L2-normalize rows of x (f32) -> bf16, one wave per row.
// ---------------------------------------------------------------------------
__global__ __launch_bounds__(256) void k_normx(const float* __restrict__ x,
                                               unsigned short* __restrict__ xb) {
    int row  = blockIdx.x * 4 + (threadIdx.x >> 6);
    int lane = threadIdx.x & 63;
    const float4* xr = (const float4*)(x + (size_t)row * EMB);
    float4 a = xr[lane * 2];
    float4 b = xr[lane * 2 + 1];
    float ss = a.x*a.x + a.y*a.y + a.z*a.z + a.w*a.w
             + b.x*b.x + b.y*b.y + b.z*b.z + b.w*b.w;
#pragma unroll
    for (int d = 1; d < 64; d <<= 1) ss += __shfl_xor(ss, d);
    float rn = 1.0f / fmaxf(sqrtf(ss), 1e-12f);
    int4 o;
    o.x = f2bf(a.x * rn) | (f2bf(a.y * rn) << 16);
    o.y = f2bf(a.z * rn) | (f2bf(a.w * rn) << 16);
    o.z = f2bf(b.x * rn) | (f2bf(b.y * rn) << 16);
    o.w = f2bf(b.z * rn) | (f2bf(b.w * rn) << 16);
    ((int4*)(xb + (size_t)row * EMB))[lane] = o;
}

// ---------------------------------------------------------------------------
// k_tgt: exact f32 target logit per row: s*cos and s*phi at the label.
// ---------------------------------------------------------------------------
__global__ __launch_bounds__(512) void k_tgt(const float* __restrict__ x,
                                             const float* __restrict__ W,
                                             const long long* __restrict__ label,
                                             float* __restrict__ tcos,
                                             float* __restrict__ tphi) {
    int m    = blockIdx.x * 8 + (threadIdx.x >> 6);
    int lane = threadIdx.x & 63;
    int lb   = (int)label[m];
    const float4* xr = (const float4*)(x + (size_t)m  * EMB);
    const float4* wr = (const float4*)(W + (size_t)lb * EMB);
    float sx = 0.f, sw = 0.f, sd = 0.f;
#pragma unroll
    for (int q = 0; q < 2; ++q) {
        float4 a = xr[lane * 2 + q];
        float4 b = wr[lane * 2 + q];
        sx += a.x*a.x + a.y*a.y + a.z*a.z + a.w*a.w;
        sw += b.x*b.x + b.y*b.y + b.z*b.z + b.w*b.w;
        sd += a.x*b.x + a.y*b.y + a.z*b.z + a.w*b.w;
    }
#pragma unroll
    for (int d = 1; d < 64; d <<= 1) {
        sx += __shfl_xor(sx, d);
        sw += __shfl_xor(sw, d);
        sd += __shfl_xor(sd, d);
    }
    if (lane == 0) {
        float cv = sd / (fmaxf(sqrtf(sx), 1e-12f) * fmaxf(sqrtf(sw), 1e-12f));
        float sine = sqrtf(fmaxf(0.f, 1.f - cv * cv));
        float phi  = cv * COS_M - sine * SIN_M;
        if (!(cv > TH_C)) phi = cv - MM_C;
        tcos[m] = S_SCALE * cv;
        tphi[m] = S_SCALE * phi;
    }
}

// ---------------------------------------------------------------------------
// k_prep: W f32 -> Wb bf16 with S/||w|| folded in, PRE-SWIZZLED so k_mainF's
// staging is a linear memcpy-to-LDS and its swizzled ds_reads see the right
// bytes. One wave per class. Nontemporal W reads (zero reuse).
// ---------------------------------------------------------------------------
__global__ __launch_bounds__(256) void k_prep(const float* __restrict__ W,
                                              unsigned short* __restrict__ Wb) {
    int w    = blockIdx.x * 4 + (threadIdx.x >> 6);
    int lane = threadIdx.x & 63;
    const f32x4* r = (const f32x4*)(W + (size_t)w * EMB);
    f32x4 a = __builtin_nontemporal_load(r + lane * 2);
    f32x4 b = __builtin_nontemporal_load(r + lane * 2 + 1);
    float ss = a[0]*a[0] + a[1]*a[1] + a[2]*a[2] + a[3]*a[3]
             + b[0]*b[0] + b[1]*b[1] + b[2]*b[2] + b[3]*b[3];
#pragma unroll
    for (int d = 1; d < 64; d <<= 1) ss += __shfl_xor(ss, d);
    float rn = S_SCALE / fmaxf(sqrtf(ss), 1e-12f);
    uint4 o;
    o.x = f2bf(a[0]*rn) | (f2bf(a[1]*rn) << 16);
    o.y = f2bf(a[2]*rn) | (f2bf(a[3]*rn) << 16);
    o.z = f2bf(b[0]*rn) | (f2bf(b[1]*rn) << 16);
    o.w = f2bf(b[2]*rn) | (f2bf(b[3]*rn) << 16);
    *(uint4*)((char*)Wb + (size_t)w * 1024 + ((unsigned)(lane ^ (w & 7)) << 4)) = o;
}

// ---------------------------------------------------------------------------
// k_mainF: A-in-registers streaming GEMM + per-lane online LSE.
// Grid = 2 row-groups x 128 chunk-columns (256 blocks, 512 thr, 1/CU,
// __launch_bounds__(512,2) -> 256-VGPR budget). Wave = 32 rows x 32 classes:
// A (32 rows x 512 k) lives in 32 bf8 regs (128 VGPR), loaded ONCE; each B
// ds_read feeds TWO MFMAs (halves LDS traffic vs 16-row tile). k-loop is
// pure LDS+MFMA: 16 x (2 swizzled ds_read_b128 + 4 MFMA). B staged via 4
// global_load_lds/wave, counted vmcnt(4), raw barriers.
// ---------------------------------------------------------------------------
__global__ __launch_bounds__(512, 2) void k_mainF(
        const unsigned short* __restrict__ Wb,
        const unsigned short* __restrict__ xb,
        float2* __restrict__ pms) {
    __shared__ __align__(16) unsigned short Bl[2][BNF * EMB];  // 2 x 32 KiB

    const int tid  = threadIdx.x;
    const int lane = tid & 63;
    const int wv   = tid >> 6;           // wave 0..7
    const int l15  = lane & 15;
    const int lg   = lane >> 4;
    const int bc   = blockIdx.x & (NBC - 1);   // chunk column
    const int rg   = blockIdx.x >> 7;          // row group (0..1)

    // ---- A into registers: rows rg*256 + wv*32 + {0,16} + l15, all K ----
    const unsigned short* xp = xb + (size_t)(rg * 256 + wv * 32 + l15) * EMB;
    bf8 a0[16], a1[16];
#pragma unroll
    for (int ks = 0; ks < 16; ++ks) {
        a0[ks] = *(const bf8*)(xp + ks * 32 + lg * 8);
        a1[ks] = *(const bf8*)(xp + 16 * EMB + ks * 32 + lg * 8);
    }

    // per-lane online-softmax state per (row-frag, i)
    float Mr[2][4], Sr[2][4];
#pragma unroll
    for (int mf = 0; mf < 2; ++mf)
#pragma unroll
        for (int i = 0; i < 4; ++i) { Mr[mf][i] = -1e38f; Sr[mf][i] = 0.0f; }

    const char* WbB = (const char*)Wb;
    auto issue = [&](int ci, int b) {
        const char* src = WbB + (size_t)ci * (BNF * EMB * 2) + wv * 4096 + lane * 16;
        char* dst = (char*)&Bl[b][0] + wv * 4096;   // wave-uniform base
#pragma unroll
        for (int r2 = 0; r2 < 4; ++r2)
            __builtin_amdgcn_global_load_lds(
                (const __attribute__((address_space(1))) unsigned int*)(src + r2 * 1024),
                (__attribute__((address_space(3))) unsigned int*)(dst + r2 * 1024),
                16, 0, 0);
    };

    issue(bc, 0);
    int buf = 0;
    for (int ci = bc; ci < NCHUNK; ci += NBC) {
        int cn = ci + NBC;
        if (cn < NCHUNK) {
            issue(cn, buf ^ 1);
            asm volatile("s_waitcnt vmcnt(4)" ::: "memory");   // current buf ready
        } else {
            asm volatile("s_waitcnt vmcnt(0)" ::: "memory");
        }
        __builtin_amdgcn_sched_barrier(0);
        __builtin_amdgcn_s_barrier();
        __builtin_amdgcn_sched_barrier(0);

        // ---- pure LDS+MFMA k-loop: 32 rows x 32 classes per wave ----
        f4 acc00, acc01, acc10, acc11;
#pragma unroll
        for (int i = 0; i < 4; ++i) {
            acc00[i] = 0.0f; acc01[i] = 0.0f;
            acc10[i] = 0.0f; acc11[i] = 0.0f;
        }

        const char* BB = (const char*)&Bl[buf][0];
#pragma unroll
        for (int ks = 0; ks < 16; ++ks) {
            int sx = (((ks * 4 + lg) ^ (l15 & 7)) << 4);   // swizzled byte off
            bf8 b0 = *(const bf8*)(BB + l15 * 1024 + sx);
            bf8 b1 = *(const bf8*)(BB + (16 + l15) * 1024 + sx);
            acc00 = __builtin_amdgcn_mfma_f32_16x16x32_bf16(a0[ks], b0, acc00, 0, 0, 0);
            acc01 = __builtin_amdgcn_mfma_f32_16x16x32_bf16(a0[ks], b1, acc01, 0, 0, 0);
            acc10 = __builtin_amdgcn_mfma_f32_16x16x32_bf16(a1[ks], b0, acc10, 0, 0, 0);
            acc11 = __builtin_amdgcn_mfma_f32_16x16x32_bf16(a1[ks], b1, acc11, 0, 0, 0);
        }

        // ---- epilogue: logits ARE acc (S/||w|| baked) -> online (M,S) ----
#pragma unroll
        for (int i = 0; i < 4; ++i) {
            float v0 = acc00[i], v1 = acc01[i];
            float pm = fmaxf(v0, v1);
            float nM = fmaxf(Mr[0][i], pm);
            Sr[0][i] = Sr[0][i] * __expf(Mr[0][i] - nM)
                     + __expf(v0 - nM) + __expf(v1 - nM);
            Mr[0][i] = nM;
            float w0 = acc10[i], w1 = acc11[i];
            float qm = fmaxf(w0, w1);
            float nN = fmaxf(Mr[1][i], qm);
            Sr[1][i] = Sr[1][i] * __expf(Mr[1][i] - nN)
                     + __expf(w0 - nN) + __expf(w1 - nN);
            Mr[1][i] = nN;
        }

        __builtin_amdgcn_sched_barrier(0);
        __builtin_amdgcn_s_barrier();       // all waves done reading Bl[buf]
        __builtin_amdgcn_sched_barrier(0);
        buf ^= 1;
    }

    // ---- merge (M,S) across the 16 column-lanes, one write per row ----
#pragma unroll
    for (int mf = 0; mf < 2; ++mf)
#pragma unroll
        for (int i = 0; i < 4; ++i) {
            float M = Mr[mf][i], S = Sr[mf][i];
#pragma unroll
            for (int d = 1; d < 16; d <<= 1) {
                float oM = __shfl_xor(M, d), oS = __shfl_xor(S, d);
                float nM = fmaxf(M, oM);
                S = S * __expf(M - nM) + oS * __expf(oM - nM);
                M = nM;
            }
            if (l15 == 0) {
                int m = rg * 256 + wv * 32 + mf * 16 + lg * 4 + i;
                pms[(size_t)bc * BATCH + m] = make_float2(M, S);
            }
        }
}

// ---------------------------------------------------------------------------
// k_mainS: fallback (round-7 structure) if ws can't hold Wb.
// ---------------------------------------------------------------------------
__global__ __launch_bounds__(1024, 4) void k_mainS(
        const float* __restrict__ W, const unsigned short* __restrict__ xb,
        float2* __restrict__ pms) {
    __shared__ __align__(16) char B32[BN * EMB * 4];
    __shared__ float ssq[BN];

    const int tid  = threadIdx.x;
    const int lane = tid & 63;
    const int wv   = tid >> 6;
    const int l15  = lane & 15;
    const int lg   = lane >> 4;
    const int sw   = (l15 & 7) << 4;
    const unsigned short* xp = xb + (size_t)(wv * 32 + l15) * EMB;

    float Mr[2][4], Sr[2][4];
#pragma unroll
    for (int mf = 0; mf < 2; ++mf)
#pragma unroll
        for (int i = 0; i < 4; ++i) { Mr[mf][i] = -1e38f; Sr[mf][i] = 0.0f; }

    auto issue4 = [&](int ci, int qb) {
#pragma unroll
        for (int q = qb; q < qb + 4; ++q) {
            int unit = q * 1024 + tid;
            int c    = ci * BN + (unit >> 7);
            if (c > NUM_CLASSES - 1) c = NUM_CLASSES - 1;
            const char* src = (const char*)W + (size_t)c * (EMB * 4)
                            + (unit & 127) * 16;
            __builtin_amdgcn_global_load_lds(
                (const __attribute__((address_space(1))) unsigned int*)src,
                (__attribute__((address_space(3))) unsigned int*)
                    (B32 + q * 16384 + wv * 1024),
                16, 0, 0);
        }
    };

    issue4(blockIdx.x, 0);
    issue4(blockIdx.x, 4);

    for (int ci = blockIdx.x; ci < NBLK; ci += GRID_S) {
        asm volatile("s_waitcnt vmcnt(0)" ::: "memory");
        __builtin_amdgcn_sched_barrier(0);
        __builtin_amdgcn_s_barrier();

        if (tid < BN) ssq[tid] = 0.0f;

        const float4* Bf = (const float4*)B32;
        float4 r[8];
#pragma unroll
        for (int q = 0; q < 8; ++q) r[q] = Bf[q * 1024 + tid];
        float sq[8];
#pragma unroll
        for (int q = 0; q < 8; ++q)
            sq[q] = r[q].x*r[q].x + r[q].y*r[q].y + r[q].z*r[q].z + r[q].w*r[q].w;

        asm volatile("s_waitcnt lgkmcnt(0)" ::: "memory");
        __builtin_amdgcn_sched_barrier(0);
        __builtin_amdgcn_s_barrier();

        const bool has = (ci + GRID_S) < NBLK;
        if (has) issue4(ci + GRID_S, 4);

        const int kb = (tid & 127) * 8;
#pragma unroll
        for (int q = 0; q < 8; ++q) {
            int cls = q * 8 + (tid >> 7);
            unsigned lo, hi;
            asm("v_cvt_pk_bf16_f32 %0, %1, %2" : "=v"(lo) : "v"(r[q].x), "v"(r[q].y));
            asm("v_cvt_pk_bf16_f32 %0, %1, %2" : "=v"(hi) : "v"(r[q].z), "v"(r[q].w));
            *(uint2*)(B32 + cls * 1024 + (kb ^ ((cls & 7) << 4))) = make_uint2(lo, hi);
        }
#pragma unroll
        for (int q = 0; q < 8; ++q) {
            float s = sq[q];
            s += __shfl_xor(s, 1);  s += __shfl_xor(s, 2);  s += __shfl_xor(s, 4);
            s += __shfl_xor(s, 8);  s += __shfl_xor(s, 16); s += __shfl_xor(s, 32);
            if (lane == 0) atomicAdd(&ssq[q * 8 + (tid >> 7)], s);
        }

        asm volatile("s_waitcnt lgkmcnt(0)" ::: "memory");
        __builtin_amdgcn_sched_barrier(0);
        __builtin_amdgcn_s_barrier();

        f4 acc[2][4];
#pragma unroll
        for (int mf = 0; mf < 2; ++mf)
#pragma unroll
            for (int nf = 0; nf < 4; ++nf)
#pragma unroll
                for (int i = 0; i < 4; ++i) acc[mf][nf][i] = 0.0f;

#pragma unroll 4
        for (int k0 = 0; k0 < EMB; k0 += 32) {
            int kb2 = k0 * 2 + lg * 16;
            bf8 b0 = *(const bf8*)(B32 + (0 * 16 + l15) * 1024 + (kb2 ^ sw));
            bf8 b1 = *(const bf8*)(B32 + (1 * 16 + l15) * 1024 + (kb2 ^ sw));
            bf8 b2 = *(const bf8*)(B32 + (2 * 16 + l15) * 1024 + (kb2 ^ sw));
            bf8 b3 = *(const bf8*)(B32 + (3 * 16 + l15) * 1024 + (kb2 ^ sw));
            bf8 a0 = *(const bf8*)(xp + k0 + lg * 8);
            bf8 a1 = *(const bf8*)(xp + 16 * EMB + k0 + lg * 8);
            acc[0][0] = __builtin_amdgcn_mfma_f32_16x16x32_bf16(a0, b0, acc[0][0], 0, 0, 0);
            acc[0][1] = __builtin_amdgcn_mfma_f32_16x16x32_bf16(a0, b1, acc[0][1], 0, 0, 0);
            acc[0][2] = __builtin_amdgcn_mfma_f32_16x16x32_bf16(a0, b2, acc[0][2], 0, 0, 0);
            acc[0][3] = __builtin_amdgcn_mfma_f32_16x16x32_bf16(a0, b3, acc[0][3], 0, 0, 0);
            acc[1][0] = __builtin_amdgcn_mfma_f32_16x16x32_bf16(a1, b0, acc[1][0], 0, 0, 0);
            acc[1][1] = __builtin_amdgcn_mfma_f32_16x16x32_bf16(a1, b1, acc[1][1], 0, 0, 0);
            acc[1][2] = __builtin_amdgcn_mfma_f32_16x16x32_bf16(a1, b2, acc[1][2], 0, 0, 0);
            acc[1][3] = __builtin_amdgcn_mfma_f32_16x16x32_bf16(a1, b3, acc[1][3], 0, 0, 0);
        }

        float rn[4];
#pragma unroll
        for (int nf = 0; nf < 4; ++nf)
            rn[nf] = S_SCALE / fmaxf(sqrtf(ssq[nf * 16 + l15]), 1e-12f);
        const int  c0   = ci * BN;
        const bool tail = (c0 + BN > NUM_CLASSES);
#pragma unroll
        for (int mf = 0; mf < 2; ++mf)
#pragma unroll
            for (int i = 0; i < 4; ++i) {
                float v0 = acc[mf][0][i] * rn[0];
                float v1 = acc[mf][1][i] * rn[1];
                float v2 = acc[mf][2][i] * rn[2];
                float v3 = acc[mf][3][i] * rn[3];
                if (tail) {
                    if (c0 + 0 * 16 + l15 >= NUM_CLASSES) v0 = -1e30f;
                    if (c0 + 1 * 16 + l15 >= NUM_CLASSES) v1 = -1e30f;
                    if (c0 + 2 * 16 + l15 >= NUM_CLASSES) v2 = -1e30f;
                    if (c0 + 3 * 16 + l15 >= NUM_CLASSES) v3 = -1e30f;
                }
                float pm = fmaxf(fmaxf(v0, v1), fmaxf(v2, v3));
                float nM = fmaxf(Mr[mf][i], pm);
                Sr[mf][i] = Sr[mf][i] * __expf(Mr[mf][i] - nM)
                          + __expf(v0 - nM) + __expf(v1 - nM)
                          + __expf(v2 - nM) + __expf(v3 - nM);
                Mr[mf][i] = nM;
            }

        __builtin_amdgcn_sched_barrier(0);
        __builtin_amdgcn_s_barrier();
        if (has) issue4(ci + GRID_S, 0);
    }

#pragma unroll
    for (int mf = 0; mf < 2; ++mf)
#pragma unroll
        for (int i = 0; i < 4; ++i) {
            float M = Mr[mf][i], S = Sr[mf][i];
#pragma unroll
            for (int d = 1; d < 16; d <<= 1) {
                float oM = __shfl_xor(M, d), oS = __shfl_xor(S, d);
                float nM = fmaxf(M, oM);
                S = S * __expf(M - nM) + oS * __expf(oM - nM);
                M = nM;
            }
            if (l15 == 0) {
                int m = wv * 32 + mf * 16 + lg * 4 + i;
                pms[(size_t)blockIdx.x * BATCH + m] = make_float2(M, S);
            }
        }
}

// ---------------------------------------------------------------------------
// k_red: merge Q column-partials per reduction slot, coalesced.
// ---------------------------------------------------------------------------
__global__ __launch_bounds__(512) void k_red(const float2* __restrict__ pms,
                                             float2* __restrict__ part, int Q) {
    int t = threadIdx.x, b = blockIdx.x;
    float M = -1e38f, S = 0.f;
    for (int q = 0; q < Q; ++q) {
        float2 v = pms[(size_t)(b * Q + q) * BATCH + t];
        float nM = fmaxf(M, v.x);
        S = S * __expf(M - nM) + v.y * __expf(v.x - nM);
        M = nM;
    }
    part[b * BATCH + t] = make_float2(M, S);
}

// ---------------------------------------------------------------------------
// k_fin: merge 64 partials per row, patch label col (plain->margin), mean.
// ---------------------------------------------------------------------------
__global__ __launch_bounds__(512) void k_fin(const float2* __restrict__ part,
                                             const float* __restrict__ tcos,
                                             const float* __restrict__ tphi,
                                             float* __restrict__ out) {
    int t = threadIdx.x;
    float M = -1e38f, S = 0.f;
    for (int b = 0; b < RBLK; ++b) {
        float2 v = part[b * BATCH + t];
        float nM = fmaxf(M, v.x);
        S = S * __expf(M - nM) + v.y * __expf(v.x - nM);
        M = nM;
    }
    float Sc = S - __expf(tcos[t] - M) + __expf(tphi[t] - M);
    Sc = fmaxf(Sc, 1e-30f);
    float loss = M + logf(Sc) - tphi[t];
#pragma unroll
    for (int d = 1; d < 64; d <<= 1) loss += __shfl_xor(loss, d);
    __shared__ float wred[8];
    if ((t & 63) == 0) wred[t >> 6] = loss;
    __syncthreads();
    if (t == 0) {
        float s = 0.f;
        for (int w = 0; w < 8; ++w) s += wred[w];
        out[0] = s / (float)BATCH;
    }
}

extern "C" void kernel_launch(void* const* d_in, const int* in_sizes, int n_in,
                              void* d_out, int out_size, void* d_ws, size_t ws_size,
                              hipStream_t stream) {
    const float*     x     = (const float*)d_in[0];
    const long long* label = (const long long*)d_in[1];
    const float*     W     = (const float*)d_in[2];
    float*           out   = (float*)d_out;

    // workspace layout
    char* ws = (char*)d_ws;
    unsigned short* xb   = (unsigned short*)ws;              // 524288
    float*          tcos = (float*)(ws + 524288);            // 2048
    float*          tphi = (float*)(ws + 526336);            // 2048
    float2*         pms  = (float2*)(ws + 528384);           // 1048576 (max path)
    float2*         part = (float2*)(ws + 1576960);          // 262144
    unsigned short* Wb   = (unsigned short*)(ws + 1839104);  // 100000*1024 B
    const size_t WS_NEED = 1839104ull + (size_t)NUM_CLASSES * 1024;

    k_normx<<<BATCH / 4, 256, 0, stream>>>(x, xb);
    k_tgt  <<<BATCH / 8, 512, 0, stream>>>(x, W, label, tcos, tphi);
    if (ws_size >= WS_NEED) {
        k_prep <<<NUM_CLASSES / 4, 256, 0, stream>>>(W, Wb);
        k_mainF<<<GRID_F, 512,  0, stream>>>(Wb, xb, pms);
        k_red  <<<RBLK,   512,  0, stream>>>(pms, part, NBC / RBLK);
    } else {
        k_mainS<<<GRID_S, 1024, 0, stream>>>(W, xb, pms);
        k_red  <<<RBLK,   512,  0, stream>>>(pms, part, GRID_S / RBLK);
    }
    k_fin<<<1, 512, 0, stream>>>(part, tcos, tphi, out);
}

// Round 11
// 113.010 us; speedup vs baseline: 2.3134x; 1.0876x over previous
//
#include <hip/hip_runtime.h>
#include <math.h>

#define NUM_CLASSES 100000
#define EMB 512
#define BATCH 512

#define BNF 32                        /* classes per chunk */
#define NCHUNK (NUM_CLASSES / BNF)    /* 3125, exact — no tail */
#define NBC 128                       /* chunk columns */
#define GRID_F 256                    /* 2 row-groups x 128 cols, 1 block/CU */
#define RBLK 64

// ArcFace constants (margin m=0.3, scale s=120)
#define S_SCALE 120.0f
#define COS_M   0.9553364891256061f
#define SIN_M   0.29552020666133955f
#define TH_C   (-0.9553364891256061f)
#define MM_C    0.08865606199840187f

typedef short bf8 __attribute__((ext_vector_type(8)));   // 8 x bf16
typedef float f4  __attribute__((ext_vector_type(4)));   // MFMA accumulator
typedef float f32x4 __attribute__((ext_vector_type(4)));

__device__ __forceinline__ unsigned short f2bf(float f) {
    union { float f; unsigned u; } a; a.f = f;
    unsigned r = a.u + 0x7fffu + ((a.u >> 16) & 1u);
    return (unsigned short)(r >> 16);
}

// ---------------------------------------------------------------------------
// k_normx: L2-normalize rows of x (f32) -> bf16, one wave per row.
// ---------------------------------------------------------------------------
__global__ __launch_bounds__(256) void k_normx(const float* __restrict__ x,
                                               unsigned short* __restrict__ xb) {
    int row  = blockIdx.x * 4 + (threadIdx.x >> 6);
    int lane = threadIdx.x & 63;
    const float4* xr = (const float4*)(x + (size_t)row * EMB);
    float4 a = xr[lane * 2];
    float4 b = xr[lane * 2 + 1];
    float ss = a.x*a.x + a.y*a.y + a.z*a.z + a.w*a.w
             + b.x*b.x + b.y*b.y + b.z*b.z + b.w*b.w;
#pragma unroll
    for (int d = 1; d < 64; d <<= 1) ss += __shfl_xor(ss, d);
    float rn = 1.0f / fmaxf(sqrtf(ss), 1e-12f);
    int4 o;
    o.x = f2bf(a.x * rn) | (f2bf(a.y * rn) << 16);
    o.y = f2bf(a.z * rn) | (f2bf(a.w * rn) << 16);
    o.z = f2bf(b.x * rn) | (f2bf(b.y * rn) << 16);
    o.w = f2bf(b.z * rn) | (f2bf(b.w * rn) << 16);
    ((int4*)(xb + (size_t)row * EMB))[lane] = o;
}

// ---------------------------------------------------------------------------
// k_tgt: exact f32 target logit per row: s*cos and s*phi at the label.
// ---------------------------------------------------------------------------
__global__ __launch_bounds__(512) void k_tgt(const float* __restrict__ x,
                                             const float* __restrict__ W,
                                             const long long* __restrict__ label,
                                             float* __restrict__ tcos,
                                             float* __restrict__ tphi) {
    int m    = blockIdx.x * 8 + (threadIdx.x >> 6);
    int lane = threadIdx.x & 63;
    int lb   = (int)label[m];
    const float4* xr = (const float4*)(x + (size_t)m  * EMB);
    const float4* wr = (const float4*)(W + (size_t)lb * EMB);
    float sx = 0.f, sw = 0.f, sd = 0.f;
#pragma unroll
    for (int q = 0; q < 2; ++q) {
        float4 a = xr[lane * 2 + q];
        float4 b = wr[lane * 2 + q];
        sx += a.x*a.x + a.y*a.y + a.z*a.z + a.w*a.w;
        sw += b.x*b.x + b.y*b.y + b.z*b.z + b.w*b.w;
        sd += a.x*b.x + a.y*b.y + a.z*b.z + a.w*b.w;
    }
#pragma unroll
    for (int d = 1; d < 64; d <<= 1) {
        sx += __shfl_xor(sx, d);
        sw += __shfl_xor(sw, d);
        sd += __shfl_xor(sd, d);
    }
    if (lane == 0) {
        float cv = sd / (fmaxf(sqrtf(sx), 1e-12f) * fmaxf(sqrtf(sw), 1e-12f));
        float sine = sqrtf(fmaxf(0.f, 1.f - cv * cv));
        float phi  = cv * COS_M - sine * SIN_M;
        if (!(cv > TH_C)) phi = cv - MM_C;
        tcos[m] = S_SCALE * cv;
        tphi[m] = S_SCALE * phi;
    }
}

// ---------------------------------------------------------------------------
// k_fused: single pass over W. A-in-registers GEMM + in-kernel f32->bf16
// convert with S/||w|| folded in + per-lane online LSE.
// Grid 256 = 2 row-groups x 128 chunk-cols; twins (bc,rg0/1) placed 8 apart
// so they share an XCD (L2 dedup of the W stream). 512 thr, 1 block/CU,
// __launch_bounds__(512,2) -> 256-VGPR budget.
// Per 32-class chunk, per wave (owns a 4-class / 8 KB f32 slab, self-staged
// via global_load_lds -> per-wave vmcnt, no barrier for arrival):
//   vmcnt(0) -> ds_read slab to 32 regs -> lgkm -> re-issue slab for chunk
//   n+2 -> wave-reduce ssq (4 classes) -> rn=S*rsqrt -> cvt_pk -> swizzled
//   ds_write into bf16 dbuf -> k-loop (16 x {2 ds_read_b128 + 4 MFMA}) on
//   current bf16 buffer -> online (M,S) -> ONE barrier.
// LDS: 64K f32 + 2x32K bf16 = 128 KiB.
// ---------------------------------------------------------------------------
__global__ __launch_bounds__(512, 2) void k_fused(
        const float* __restrict__ W, const unsigned short* __restrict__ xb,
        float2* __restrict__ pms) {
    __shared__ __align__(16) char B32[8 * 8192];               // f32 staging
    __shared__ __align__(16) unsigned short Bb[2][BNF * EMB];  // 2 x 32 KiB

    const int tid  = threadIdx.x;
    const int lane = tid & 63;
    const int wv   = tid >> 6;                 // wave 0..7
    const int l15  = lane & 15;
    const int lg   = lane >> 4;
    const int bc   = (blockIdx.x & 7) | ((blockIdx.x >> 4) << 3);  // 0..127
    const int rg   = (blockIdx.x >> 3) & 1;                        // row group

    // ---- A into registers: rows rg*256 + wv*32 + {0,16} + l15, all K ----
    const unsigned short* xp = xb + (size_t)(rg * 256 + wv * 32 + l15) * EMB;
    bf8 a0[16], a1[16];
#pragma unroll
    for (int ks = 0; ks < 16; ++ks) {
        a0[ks] = *(const bf8*)(xp + ks * 32 + lg * 8);
        a1[ks] = *(const bf8*)(xp + 16 * EMB + ks * 32 + lg * 8);
    }

    float Mr[2][4], Sr[2][4];
#pragma unroll
    for (int mf = 0; mf < 2; ++mf)
#pragma unroll
        for (int i = 0; i < 4; ++i) { Mr[mf][i] = -1e38f; Sr[mf][i] = 0.0f; }

    const char* Wbase = (const char*)W;

    // issue this wave's 8 KB slab (4 classes) of chunk ci into its B32 region
    auto issue = [&](int ci) {
        const char* src = Wbase + (size_t)ci * (BNF * EMB * 4)
                        + wv * 8192 + lane * 16;
        char* dst = B32 + wv * 8192;
#pragma unroll
        for (int q = 0; q < 8; ++q)
            __builtin_amdgcn_global_load_lds(
                (const __attribute__((address_space(1))) unsigned int*)(src + q * 1024),
                (__attribute__((address_space(3))) unsigned int*)(dst + q * 1024),
                16, 0, 0);
    };

    // convert chunk ci (f32 in own slab) -> Bb[b]; re-issue slab for nxt
    auto conv = [&](int b, int nxt) {
        asm volatile("s_waitcnt vmcnt(0)" ::: "memory");   // own slab arrived
        __builtin_amdgcn_sched_barrier(0);
        const f32x4* Bf = (const f32x4*)(B32 + wv * 8192);
        f32x4 r[8];
#pragma unroll
        for (int k = 0; k < 8; ++k) r[k] = Bf[k * 64 + lane];
        asm volatile("s_waitcnt lgkmcnt(0)" ::: "memory"); // reads retired
        __builtin_amdgcn_sched_barrier(0);
        if (nxt < NCHUNK) issue(nxt);                      // slab now dead
        // per-class sum of squares (class c = k>>1), wave-wide reduce
        float sq[4];
#pragma unroll
        for (int c = 0; c < 4; ++c) {
            f32x4 u = r[2 * c], v = r[2 * c + 1];
            sq[c] = u[0]*u[0] + u[1]*u[1] + u[2]*u[2] + u[3]*u[3]
                  + v[0]*v[0] + v[1]*v[1] + v[2]*v[2] + v[3]*v[3];
        }
#pragma unroll
        for (int d = 1; d < 64; d <<= 1)
#pragma unroll
            for (int c = 0; c < 4; ++c) sq[c] += __shfl_xor(sq[c], d);
        float rn[4];
#pragma unroll
        for (int c = 0; c < 4; ++c)
            rn[c] = S_SCALE / fmaxf(sqrtf(sq[c]), 1e-12f);
        // scale + cvt + swizzled bf16 write
        char* bb = (char*)&Bb[b][0];
#pragma unroll
        for (int k = 0; k < 8; ++k) {
            int c = k >> 1;
            float v0 = r[k][0] * rn[c], v1 = r[k][1] * rn[c];
            float v2 = r[k][2] * rn[c], v3 = r[k][3] * rn[c];
            unsigned lo, hi;
            asm("v_cvt_pk_bf16_f32 %0, %1, %2" : "=v"(lo) : "v"(v0), "v"(v1));
            asm("v_cvt_pk_bf16_f32 %0, %1, %2" : "=v"(hi) : "v"(v2), "v"(v3));
            int cc = wv * 4 + c;                           // class row 0..31
            int fj = ((k & 1) << 5) + (lane >> 1);         // 16B unit 0..63
            int ad = cc * 1024 + ((fj ^ (cc & 7)) << 4) + ((lane & 1) << 3);
            *(uint2*)(bb + ad) = make_uint2(lo, hi);
        }
    };

    // ---- prologue ----
    issue(bc);
    conv(0, bc + NBC);
    asm volatile("s_waitcnt lgkmcnt(0)" ::: "memory");
    __builtin_amdgcn_sched_barrier(0);
    __builtin_amdgcn_s_barrier();
    __builtin_amdgcn_sched_barrier(0);

    int buf = 0;
    for (int ci = bc; ci < NCHUNK; ci += NBC) {
        int cn = ci + NBC;
        if (cn < NCHUNK) conv(buf ^ 1, cn + NBC);   // prepare next chunk

        // ---- k-loop: 32 rows x 32 classes per wave, pure LDS+MFMA ----
        f4 acc00, acc01, acc10, acc11;
#pragma unroll
        for (int i = 0; i < 4; ++i) {
            acc00[i] = 0.0f; acc01[i] = 0.0f;
            acc10[i] = 0.0f; acc11[i] = 0.0f;
        }
        const char* BB = (const char*)&Bb[buf][0];
#pragma unroll
        for (int ks = 0; ks < 16; ++ks) {
            int sx = (((ks * 4 + lg) ^ (l15 & 7)) << 4);
            bf8 b0 = *(const bf8*)(BB + l15 * 1024 + sx);
            bf8 b1 = *(const bf8*)(BB + (16 + l15) * 1024 + sx);
            acc00 = __builtin_amdgcn_mfma_f32_16x16x32_bf16(a0[ks], b0, acc00, 0, 0, 0);
            acc01 = __builtin_amdgcn_mfma_f32_16x16x32_bf16(a0[ks], b1, acc01, 0, 0, 0);
            acc10 = __builtin_amdgcn_mfma_f32_16x16x32_bf16(a1[ks], b0, acc10, 0, 0, 0);
            acc11 = __builtin_amdgcn_mfma_f32_16x16x32_bf16(a1[ks], b1, acc11, 0, 0, 0);
        }

        // ---- epilogue: logits ARE acc -> per-lane online (M,S) ----
#pragma unroll
        for (int i = 0; i < 4; ++i) {
            float v0 = acc00[i], v1 = acc01[i];
            float pm = fmaxf(v0, v1);
            float nM = fmaxf(Mr[0][i], pm);
            Sr[0][i] = Sr[0][i] * __expf(Mr[0][i] - nM)
                     + __expf(v0 - nM) + __expf(v1 - nM);
            Mr[0][i] = nM;
            float w0 = acc10[i], w1 = acc11[i];
            float qm = fmaxf(w0, w1);
            float nN = fmaxf(Mr[1][i], qm);
            Sr[1][i] = Sr[1][i] * __expf(Mr[1][i] - nN)
                     + __expf(w0 - nN) + __expf(w1 - nN);
            Mr[1][i] = nN;
        }

        asm volatile("s_waitcnt lgkmcnt(0)" ::: "memory");  // conv writes visible
        __builtin_amdgcn_sched_barrier(0);
        __builtin_amdgcn_s_barrier();       // Bb[buf^1] ready, Bb[buf] consumed
        __builtin_amdgcn_sched_barrier(0);
        buf ^= 1;
    }

    // ---- merge (M,S) across the 16 column-lanes, one write per row ----
#pragma unroll
    for (int mf = 0; mf < 2; ++mf)
#pragma unroll
        for (int i = 0; i < 4; ++i) {
            float M = Mr[mf][i], S = Sr[mf][i];
#pragma unroll
            for (int d = 1; d < 16; d <<= 1) {
                float oM = __shfl_xor(M, d), oS = __shfl_xor(S, d);
                float nM = fmaxf(M, oM);
                S = S * __expf(M - nM) + oS * __expf(oM - nM);
                M = nM;
            }
            if (l15 == 0) {
                int m = rg * 256 + wv * 32 + mf * 16 + lg * 4 + i;
                pms[(size_t)bc * BATCH + m] = make_float2(M, S);
            }
        }
}

// ---------------------------------------------------------------------------
// k_red: merge Q column-partials per reduction slot, coalesced.
// ---------------------------------------------------------------------------
__global__ __launch_bounds__(512) void k_red(const float2* __restrict__ pms,
                                             float2* __restrict__ part, int Q) {
    int t = threadIdx.x, b = blockIdx.x;
    float M = -1e38f, S = 0.f;
    for (int q = 0; q < Q; ++q) {
        float2 v = pms[(size_t)(b * Q + q) * BATCH + t];
        float nM = fmaxf(M, v.x);
        S = S * __expf(M - nM) + v.y * __expf(v.x - nM);
        M = nM;
    }
    part[b * BATCH + t] = make_float2(M, S);
}

// ---------------------------------------------------------------------------
// k_fin: merge 64 partials per row, patch label col (plain->margin), mean.
// ---------------------------------------------------------------------------
__global__ __launch_bounds__(512) void k_fin(const float2* __restrict__ part,
                                             const float* __restrict__ tcos,
                                             const float* __restrict__ tphi,
                                             float* __restrict__ out) {
    int t = threadIdx.x;
    float M = -1e38f, S = 0.f;
    for (int b = 0; b < RBLK; ++b) {
        float2 v = part[b * BATCH + t];
        float nM = fmaxf(M, v.x);
        S = S * __expf(M - nM) + v.y * __expf(v.x - nM);
        M = nM;
    }
    float Sc = S - __expf(tcos[t] - M) + __expf(tphi[t] - M);
    Sc = fmaxf(Sc, 1e-30f);
    float loss = M + logf(Sc) - tphi[t];
#pragma unroll
    for (int d = 1; d < 64; d <<= 1) loss += __shfl_xor(loss, d);
    __shared__ float wred[8];
    if ((t & 63) == 0) wred[t >> 6] = loss;
    __syncthreads();
    if (t == 0) {
        float s = 0.f;
        for (int w = 0; w < 8; ++w) s += wred[w];
        out[0] = s / (float)BATCH;
    }
}

extern "C" void kernel_launch(void* const* d_in, const int* in_sizes, int n_in,
                              void* d_out, int out_size, void* d_ws, size_t ws_size,
                              hipStream_t stream) {
    const float*     x     = (const float*)d_in[0];
    const long long* label = (const long long*)d_in[1];
    const float*     W     = (const float*)d_in[2];
    float*           out   = (float*)d_out;

    // workspace layout (~1.3 MB)
    char* ws = (char*)d_ws;
    unsigned short* xb   = (unsigned short*)ws;              // 524288
    float*          tcos = (float*)(ws + 524288);            // 2048
    float*          tphi = (float*)(ws + 526336);            // 2048
    float2*         pms  = (float2*)(ws + 528384);           // 128*512*8 = 524288
    float2*         part = (float2*)(ws + 1052672);          // 64*512*8 = 262144

    k_normx<<<BATCH / 4, 256, 0, stream>>>(x, xb);
    k_tgt  <<<BATCH / 8, 512, 0, stream>>>(x, W, label, tcos, tphi);
    k_fused<<<GRID_F,    512, 0, stream>>>(W, xb, pms);
    k_red  <<<RBLK,      512, 0, stream>>>(pms, part, NBC / RBLK);
    k_fin  <<<1,         512, 0, stream>>>(part, tcos, tphi, out);
}

// Round 12
// 111.054 us; speedup vs baseline: 2.3542x; 1.0176x over previous
//
#include <hip/hip_runtime.h>
#include <math.h>

#define NUM_CLASSES 100000
#define EMB 512
#define BATCH 512

#define BNF 32                        /* classes per chunk */
#define NCHUNK (NUM_CLASSES / BNF)    /* 3125, exact — no tail */
#define NBC 128                       /* chunk columns */
#define GRID_F 256                    /* 2 row-groups x 128 cols, 1 block/CU */

// ArcFace constants (margin m=0.3, scale s=120)
#define S_SCALE 120.0f
#define COS_M   0.9553364891256061f
#define SIN_M   0.29552020666133955f
#define TH_C   (-0.9553364891256061f)
#define MM_C    0.08865606199840187f

typedef short bf8 __attribute__((ext_vector_type(8)));   // 8 x bf16
typedef float f4  __attribute__((ext_vector_type(4)));   // MFMA accumulator
typedef float f32x4 __attribute__((ext_vector_type(4)));

__device__ __forceinline__ unsigned short f2bf(float f) {
    union { float f; unsigned u; } a; a.f = f;
    unsigned r = a.u + 0x7fffu + ((a.u >> 16) & 1u);
    return (unsigned short)(r >> 16);
}

// ---------------------------------------------------------------------------
// k_normx: L2-normalize rows of x (f32) -> bf16, one wave per row.
// ---------------------------------------------------------------------------
__global__ __launch_bounds__(256) void k_normx(const float* __restrict__ x,
                                               unsigned short* __restrict__ xb) {
    int row  = blockIdx.x * 4 + (threadIdx.x >> 6);
    int lane = threadIdx.x & 63;
    const float4* xr = (const float4*)(x + (size_t)row * EMB);
    float4 a = xr[lane * 2];
    float4 b = xr[lane * 2 + 1];
    float ss = a.x*a.x + a.y*a.y + a.z*a.z + a.w*a.w
             + b.x*b.x + b.y*b.y + b.z*b.z + b.w*b.w;
#pragma unroll
    for (int d = 1; d < 64; d <<= 1) ss += __shfl_xor(ss, d);
    float rn = 1.0f / fmaxf(sqrtf(ss), 1e-12f);
    int4 o;
    o.x = f2bf(a.x * rn) | (f2bf(a.y * rn) << 16);
    o.y = f2bf(a.z * rn) | (f2bf(a.w * rn) << 16);
    o.z = f2bf(b.x * rn) | (f2bf(b.y * rn) << 16);
    o.w = f2bf(b.z * rn) | (f2bf(b.w * rn) << 16);
    ((int4*)(xb + (size_t)row * EMB))[lane] = o;
}

// ---------------------------------------------------------------------------
// k_tgt: exact f32 target logit per row: s*cos and s*phi at the label.
// ---------------------------------------------------------------------------
__global__ __launch_bounds__(512) void k_tgt(const float* __restrict__ x,
                                             const float* __restrict__ W,
                                             const long long* __restrict__ label,
                                             float* __restrict__ tcos,
                                             float* __restrict__ tphi) {
    int m    = blockIdx.x * 8 + (threadIdx.x >> 6);
    int lane = threadIdx.x & 63;
    int lb   = (int)label[m];
    const float4* xr = (const float4*)(x + (size_t)m  * EMB);
    const float4* wr = (const float4*)(W + (size_t)lb * EMB);
    float sx = 0.f, sw = 0.f, sd = 0.f;
#pragma unroll
    for (int q = 0; q < 2; ++q) {
        float4 a = xr[lane * 2 + q];
        float4 b = wr[lane * 2 + q];
        sx += a.x*a.x + a.y*a.y + a.z*a.z + a.w*a.w;
        sw += b.x*b.x + b.y*b.y + b.z*b.z + b.w*b.w;
        sd += a.x*b.x + a.y*b.y + a.z*b.z + a.w*b.w;
    }
#pragma unroll
    for (int d = 1; d < 64; d <<= 1) {
        sx += __shfl_xor(sx, d);
        sw += __shfl_xor(sw, d);
        sd += __shfl_xor(sd, d);
    }
    if (lane == 0) {
        float cv = sd / (fmaxf(sqrtf(sx), 1e-12f) * fmaxf(sqrtf(sw), 1e-12f));
        float sine = sqrtf(fmaxf(0.f, 1.f - cv * cv));
        float phi  = cv * COS_M - sine * SIN_M;
        if (!(cv > TH_C)) phi = cv - MM_C;
        tcos[m] = S_SCALE * cv;
        tphi[m] = S_SCALE * phi;
    }
}

// ---------------------------------------------------------------------------
// k_fused: single pass over W. A-in-registers GEMM, W staged f32->REGISTERS
// (one chunk ahead, HBM latency hidden under compute), convert with
// S/||w|| folded, swizzled bf16 ds_write, per-lane online LSE.
// Grid 256 = 2 row-groups x 128 chunk-cols; twins (bc, rg0/1) are 8 apart
// in blockIdx -> same XCD -> W stream L2-dedup. 512 thr, 1 block/CU,
// __launch_bounds__(512,2) -> 256-VGPR budget (~212 used).
// Per 32-class chunk, per wave (owns 4 classes / 8 KB):
//   conv: regs (chunk n+1 data) -> ssq wave-reduce -> rn=S*rsqrt -> cvt_pk
//         -> swizzled ds_write to Bb[buf^1]; then issue reg-loads for n+2
//   k-loop on Bb[buf]: 16 x {2 swizzled ds_read_b128 + 4 MFMA}
//   online (M,S) update; ONE barrier (lgkm drained; no VMEM waits at all).
// LDS: 2 x 32 KiB only.
// ---------------------------------------------------------------------------
__global__ __launch_bounds__(512, 2) void k_fused(
        const float* __restrict__ W, const unsigned short* __restrict__ xb,
        float2* __restrict__ pms) {
    __shared__ __align__(16) unsigned short Bb[2][BNF * EMB];  // 2 x 32 KiB

    const int tid  = threadIdx.x;
    const int lane = tid & 63;
    const int wv   = tid >> 6;                 // wave 0..7
    const int l15  = lane & 15;
    const int lg   = lane >> 4;
    const int bc   = (blockIdx.x & 7) | ((blockIdx.x >> 4) << 3);  // 0..127
    const int rg   = (blockIdx.x >> 3) & 1;                        // row group

    // ---- A into registers: rows rg*256 + wv*32 + {0,16} + l15, all K ----
    const unsigned short* xp = xb + (size_t)(rg * 256 + wv * 32 + l15) * EMB;
    bf8 a0[16], a1[16];
#pragma unroll
    for (int ks = 0; ks < 16; ++ks) {
        a0[ks] = *(const bf8*)(xp + ks * 32 + lg * 8);
        a1[ks] = *(const bf8*)(xp + 16 * EMB + ks * 32 + lg * 8);
    }

    float Mr[2][4], Sr[2][4];
#pragma unroll
    for (int mf = 0; mf < 2; ++mf)
#pragma unroll
        for (int i = 0; i < 4; ++i) { Mr[mf][i] = -1e38f; Sr[mf][i] = 0.0f; }

    const char* Wbase = (const char*)W;
    f32x4 st[8];                                // staged f32 slab (32 VGPR)

    // load this wave's 8 KB slab (4 classes) of chunk ci into registers
    auto load_st = [&](int ci) {
        const char* src = Wbase + (size_t)ci * (BNF * EMB * 4)
                        + wv * 8192 + lane * 16;
#pragma unroll
        for (int q = 0; q < 8; ++q)
            st[q] = *(const f32x4*)(src + q * 1024);
    };

    // convert slab in regs -> Bb[b] (swizzled bf16, S/||w|| folded)
    auto conv = [&](int b) {
        float sq[4];
#pragma unroll
        for (int c = 0; c < 4; ++c) {
            f32x4 u = st[2 * c], v = st[2 * c + 1];
            sq[c] = u[0]*u[0] + u[1]*u[1] + u[2]*u[2] + u[3]*u[3]
                  + v[0]*v[0] + v[1]*v[1] + v[2]*v[2] + v[3]*v[3];
        }
#pragma unroll
        for (int d = 1; d < 64; d <<= 1)
#pragma unroll
            for (int c = 0; c < 4; ++c) sq[c] += __shfl_xor(sq[c], d);
        float rn[4];
#pragma unroll
        for (int c = 0; c < 4; ++c)
            rn[c] = S_SCALE / fmaxf(sqrtf(sq[c]), 1e-12f);
        char* bb = (char*)&Bb[b][0];
#pragma unroll
        for (int k = 0; k < 8; ++k) {
            int c = k >> 1;
            float v0 = st[k][0] * rn[c], v1 = st[k][1] * rn[c];
            float v2 = st[k][2] * rn[c], v3 = st[k][3] * rn[c];
            unsigned lo, hi;
            asm("v_cvt_pk_bf16_f32 %0, %1, %2" : "=v"(lo) : "v"(v0), "v"(v1));
            asm("v_cvt_pk_bf16_f32 %0, %1, %2" : "=v"(hi) : "v"(v2), "v"(v3));
            int cc = wv * 4 + c;                           // class row 0..31
            int fj = ((k & 1) << 5) + (lane >> 1);         // 16B unit 0..63
            int ad = cc * 1024 + ((fj ^ (cc & 7)) << 4) + ((lane & 1) << 3);
            *(uint2*)(bb + ad) = make_uint2(lo, hi);
        }
    };

    // ---- prologue: chunk bc -> Bb[0]; prefetch chunk bc+NBC into regs ----
    load_st(bc);
    conv(0);
    if (bc + NBC < NCHUNK) load_st(bc + NBC);
    asm volatile("s_waitcnt lgkmcnt(0)" ::: "memory");
    __builtin_amdgcn_sched_barrier(0);
    __builtin_amdgcn_s_barrier();
    __builtin_amdgcn_sched_barrier(0);

    int buf = 0;
    for (int ci = bc; ci < NCHUNK; ci += NBC) {
        int cn = ci + NBC;
        if (cn < NCHUNK) {
            conv(buf ^ 1);                       // regs hold chunk cn
            if (cn + NBC < NCHUNK) load_st(cn + NBC);
        }

        // ---- k-loop: 32 rows x 32 classes per wave, pure LDS+MFMA ----
        f4 acc00, acc01, acc10, acc11;
#pragma unroll
        for (int i = 0; i < 4; ++i) {
            acc00[i] = 0.0f; acc01[i] = 0.0f;
            acc10[i] = 0.0f; acc11[i] = 0.0f;
        }
        const char* BB = (const char*)&Bb[buf][0];
#pragma unroll
        for (int ks = 0; ks < 16; ++ks) {
            int sx = (((ks * 4 + lg) ^ (l15 & 7)) << 4);
            bf8 b0 = *(const bf8*)(BB + l15 * 1024 + sx);
            bf8 b1 = *(const bf8*)(BB + (16 + l15) * 1024 + sx);
            acc00 = __builtin_amdgcn_mfma_f32_16x16x32_bf16(a0[ks], b0, acc00, 0, 0, 0);
            acc01 = __builtin_amdgcn_mfma_f32_16x16x32_bf16(a0[ks], b1, acc01, 0, 0, 0);
            acc10 = __builtin_amdgcn_mfma_f32_16x16x32_bf16(a1[ks], b0, acc10, 0, 0, 0);
            acc11 = __builtin_amdgcn_mfma_f32_16x16x32_bf16(a1[ks], b1, acc11, 0, 0, 0);
        }

        // ---- epilogue: logits ARE acc -> per-lane online (M,S) ----
#pragma unroll
        for (int i = 0; i < 4; ++i) {
            float v0 = acc00[i], v1 = acc01[i];
            float pm = fmaxf(v0, v1);
            float nM = fmaxf(Mr[0][i], pm);
            Sr[0][i] = Sr[0][i] * __expf(Mr[0][i] - nM)
                     + __expf(v0 - nM) + __expf(v1 - nM);
            Mr[0][i] = nM;
            float w0 = acc10[i], w1 = acc11[i];
            float qm = fmaxf(w0, w1);
            float nN = fmaxf(Mr[1][i], qm);
            Sr[1][i] = Sr[1][i] * __expf(Mr[1][i] - nN)
                     + __expf(w0 - nN) + __expf(w1 - nN);
            Mr[1][i] = nN;
        }

        asm volatile("s_waitcnt lgkmcnt(0)" ::: "memory");  // conv writes done
        __builtin_amdgcn_sched_barrier(0);
        __builtin_amdgcn_s_barrier();       // Bb[buf^1] ready, Bb[buf] consumed
        __builtin_amdgcn_sched_barrier(0);
        buf ^= 1;
    }

    // ---- merge (M,S) across the 16 column-lanes, one write per row ----
#pragma unroll
    for (int mf = 0; mf < 2; ++mf)
#pragma unroll
        for (int i = 0; i < 4; ++i) {
            float M = Mr[mf][i], S = Sr[mf][i];
#pragma unroll
            for (int d = 1; d < 16; d <<= 1) {
                float oM = __shfl_xor(M, d), oS = __shfl_xor(S, d);
                float nM = fmaxf(M, oM);
                S = S * __expf(M - nM) + oS * __expf(oM - nM);
                M = nM;
            }
            if (l15 == 0) {
                int m = rg * 256 + wv * 32 + mf * 16 + lg * 4 + i;
                pms[(size_t)bc * BATCH + m] = make_float2(M, S);
            }
        }
}

// ---------------------------------------------------------------------------
// k_fin: merge 128 column-partials per row, patch label col, loss, mean.
// ---------------------------------------------------------------------------
__global__ __launch_bounds__(512) void k_fin(const float2* __restrict__ pms,
                                             const float* __restrict__ tcos,
                                             const float* __restrict__ tphi,
                                             float* __restrict__ out) {
    int t = threadIdx.x;
    float M = -1e38f, S = 0.f;
#pragma unroll 4
    for (int b = 0; b < NBC; ++b) {
        float2 v = pms[(size_t)b * BATCH + t];
        float nM = fmaxf(M, v.x);
        S = S * __expf(M - nM) + v.y * __expf(v.x - nM);
        M = nM;
    }
    float Sc = S - __expf(tcos[t] - M) + __expf(tphi[t] - M);
    Sc = fmaxf(Sc, 1e-30f);
    float loss = M + logf(Sc) - tphi[t];
#pragma unroll
    for (int d = 1; d < 64; d <<= 1) loss += __shfl_xor(loss, d);
    __shared__ float wred[8];
    if ((t & 63) == 0) wred[t >> 6] = loss;
    __syncthreads();
    if (t == 0) {
        float s = 0.f;
        for (int w = 0; w < 8; ++w) s += wred[w];
        out[0] = s / (float)BATCH;
    }
}

extern "C" void kernel_launch(void* const* d_in, const int* in_sizes, int n_in,
                              void* d_out, int out_size, void* d_ws, size_t ws_size,
                              hipStream_t stream) {
    const float*     x     = (const float*)d_in[0];
    const long long* label = (const long long*)d_in[1];
    const float*     W     = (const float*)d_in[2];
    float*           out   = (float*)d_out;

    // workspace layout (~1.1 MB)
    char* ws = (char*)d_ws;
    unsigned short* xb   = (unsigned short*)ws;              // 524288
    float*          tcos = (float*)(ws + 524288);            // 2048
    float*          tphi = (float*)(ws + 526336);            // 2048
    float2*         pms  = (float2*)(ws + 528384);           // 128*512*8 = 524288

    k_normx<<<BATCH / 4, 256, 0, stream>>>(x, xb);
    k_tgt  <<<BATCH / 8, 512, 0, stream>>>(x, W, label, tcos, tphi);
    k_fused<<<GRID_F,    512, 0, stream>>>(W, xb, pms);
    k_fin  <<<1,         512, 0, stream>>>(pms, tcos, tphi, out);
}

// Round 13
// 99.011 us; speedup vs baseline: 2.6405x; 1.1216x over previous
//
#include <hip/hip_runtime.h>
#include <math.h>

#define NUM_CLASSES 100000
#define EMB 512
#define BATCH 512

#define BNF 32                        /* classes per chunk */
#define NCHUNK (NUM_CLASSES / BNF)    /* 3125, exact — no tail */
#define NBC 128                       /* chunk columns */
#define GRID_F 256                    /* 2 row-groups x 128 cols, 1 block/CU */

// ArcFace constants (margin m=0.3, scale s=120)
#define S_SCALE 120.0f
#define COS_M   0.9553364891256061f
#define SIN_M   0.29552020666133955f
#define TH_C   (-0.9553364891256061f)
#define MM_C    0.08865606199840187f

typedef short bf8 __attribute__((ext_vector_type(8)));   // 8 x bf16
typedef float f4  __attribute__((ext_vector_type(4)));   // MFMA accumulator
typedef float f32x4 __attribute__((ext_vector_type(4)));

__device__ __forceinline__ unsigned short f2bf(float f) {
    union { float f; unsigned u; } a; a.f = f;
    unsigned r = a.u + 0x7fffu + ((a.u >> 16) & 1u);
    return (unsigned short)(r >> 16);
}

// ---------------------------------------------------------------------------
// k_normx: L2-normalize rows of x (f32) -> bf16, one wave per row.
// ---------------------------------------------------------------------------
__global__ __launch_bounds__(256) void k_normx(const float* __restrict__ x,
                                               unsigned short* __restrict__ xb) {
    int row  = blockIdx.x * 4 + (threadIdx.x >> 6);
    int lane = threadIdx.x & 63;
    const float4* xr = (const float4*)(x + (size_t)row * EMB);
    float4 a = xr[lane * 2];
    float4 b = xr[lane * 2 + 1];
    float ss = a.x*a.x + a.y*a.y + a.z*a.z + a.w*a.w
             + b.x*b.x + b.y*b.y + b.z*b.z + b.w*b.w;
#pragma unroll
    for (int d = 1; d < 64; d <<= 1) ss += __shfl_xor(ss, d);
    float rn = 1.0f / fmaxf(sqrtf(ss), 1e-12f);
    int4 o;
    o.x = f2bf(a.x * rn) | (f2bf(a.y * rn) << 16);
    o.y = f2bf(a.z * rn) | (f2bf(a.w * rn) << 16);
    o.z = f2bf(b.x * rn) | (f2bf(b.y * rn) << 16);
    o.w = f2bf(b.z * rn) | (f2bf(b.w * rn) << 16);
    ((int4*)(xb + (size_t)row * EMB))[lane] = o;
}

// ---------------------------------------------------------------------------
// k_tgt: exact f32 target logit per row: s*cos and s*phi at the label.
// ---------------------------------------------------------------------------
__global__ __launch_bounds__(512) void k_tgt(const float* __restrict__ x,
                                             const float* __restrict__ W,
                                             const long long* __restrict__ label,
                                             float* __restrict__ tcos,
                                             float* __restrict__ tphi) {
    int m    = blockIdx.x * 8 + (threadIdx.x >> 6);
    int lane = threadIdx.x & 63;
    int lb   = (int)label[m];
    const float4* xr = (const float4*)(x + (size_t)m  * EMB);
    const float4* wr = (const float4*)(W + (size_t)lb * EMB);
    float sx = 0.f, sw = 0.f, sd = 0.f;
#pragma unroll
    for (int q = 0; q < 2; ++q) {
        float4 a = xr[lane * 2 + q];
        float4 b = wr[lane * 2 + q];
        sx += a.x*a.x + a.y*a.y + a.z*a.z + a.w*a.w;
        sw += b.x*b.x + b.y*b.y + b.z*b.z + b.w*b.w;
        sd += a.x*b.x + a.y*b.y + a.z*b.z + a.w*b.w;
    }
#pragma unroll
    for (int d = 1; d < 64; d <<= 1) {
        sx += __shfl_xor(sx, d);
        sw += __shfl_xor(sw, d);
        sd += __shfl_xor(sd, d);
    }
    if (lane == 0) {
        float cv = sd / (fmaxf(sqrtf(sx), 1e-12f) * fmaxf(sqrtf(sw), 1e-12f));
        float sine = sqrtf(fmaxf(0.f, 1.f - cv * cv));
        float phi  = cv * COS_M - sine * SIN_M;
        if (!(cv > TH_C)) phi = cv - MM_C;
        tcos[m] = S_SCALE * cv;
        tphi[m] = S_SCALE * phi;
    }
}

// ---------------------------------------------------------------------------
// k_fused: single pass over W. A-in-registers GEMM, W staged f32->REGISTERS,
// convert (S/||w|| folded) -> swizzled bf16 LDS, per-lane online LSE.
// NEW vs round 12: WAVE STAGGER — odd waves run conv(n+1) before kloop(n),
// even waves the reverse, so the block always has a DS-pipe phase and a
// VALU phase in flight (breaks the barrier phase-lock); s_setprio(1)
// around the MFMA cluster (T5 — role diversity now exists); rsqrtf norm.
// ---------------------------------------------------------------------------
__global__ __launch_bounds__(512, 2) void k_fused(
        const float* __restrict__ W, const unsigned short* __restrict__ xb,
        float2* __restrict__ pms) {
    __shared__ __align__(16) unsigned short Bb[2][BNF * EMB];  // 2 x 32 KiB

    const int tid  = threadIdx.x;
    const int lane = tid & 63;
    const int wv   = tid >> 6;                 // wave 0..7
    const int l15  = lane & 15;
    const int lg   = lane >> 4;
    const int bc   = (blockIdx.x & 7) | ((blockIdx.x >> 4) << 3);  // 0..127
    const int rg   = (blockIdx.x >> 3) & 1;                        // row group

    // ---- A into registers: rows rg*256 + wv*32 + {0,16} + l15, all K ----
    const unsigned short* xp = xb + (size_t)(rg * 256 + wv * 32 + l15) * EMB;
    bf8 a0[16], a1[16];
#pragma unroll
    for (int ks = 0; ks < 16; ++ks) {
        a0[ks] = *(const bf8*)(xp + ks * 32 + lg * 8);
        a1[ks] = *(const bf8*)(xp + 16 * EMB + ks * 32 + lg * 8);
    }

    float Mr[2][4], Sr[2][4];
#pragma unroll
    for (int mf = 0; mf < 2; ++mf)
#pragma unroll
        for (int i = 0; i < 4; ++i) { Mr[mf][i] = -1e38f; Sr[mf][i] = 0.0f; }

    const char* Wbase = (const char*)W;
    f32x4 st[8];                                // staged f32 slab (32 VGPR)

    auto load_st = [&](int ci) {
        const char* src = Wbase + (size_t)ci * (BNF * EMB * 4)
                        + wv * 8192 + lane * 16;
#pragma unroll
        for (int q = 0; q < 8; ++q)
            st[q] = *(const f32x4*)(src + q * 1024);
    };

    // convert slab in regs -> Bb[b] (swizzled bf16, S/||w|| folded)
    auto conv = [&](int b) {
        float sq[4];
#pragma unroll
        for (int c = 0; c < 4; ++c) {
            f32x4 u = st[2 * c], v = st[2 * c + 1];
            sq[c] = u[0]*u[0] + u[1]*u[1] + u[2]*u[2] + u[3]*u[3]
                  + v[0]*v[0] + v[1]*v[1] + v[2]*v[2] + v[3]*v[3];
        }
#pragma unroll
        for (int d = 1; d < 64; d <<= 1)
#pragma unroll
            for (int c = 0; c < 4; ++c) sq[c] += __shfl_xor(sq[c], d);
        float rn[4];
#pragma unroll
        for (int c = 0; c < 4; ++c)
            rn[c] = S_SCALE * rsqrtf(fmaxf(sq[c], 1e-24f));
        char* bb = (char*)&Bb[b][0];
#pragma unroll
        for (int k = 0; k < 8; ++k) {
            int c = k >> 1;
            float v0 = st[k][0] * rn[c], v1 = st[k][1] * rn[c];
            float v2 = st[k][2] * rn[c], v3 = st[k][3] * rn[c];
            unsigned lo, hi;
            asm("v_cvt_pk_bf16_f32 %0, %1, %2" : "=v"(lo) : "v"(v0), "v"(v1));
            asm("v_cvt_pk_bf16_f32 %0, %1, %2" : "=v"(hi) : "v"(v2), "v"(v3));
            int cc = wv * 4 + c;                           // class row 0..31
            int fj = ((k & 1) << 5) + (lane >> 1);         // 16B unit 0..63
            int ad = cc * 1024 + ((fj ^ (cc & 7)) << 4) + ((lane & 1) << 3);
            *(uint2*)(bb + ad) = make_uint2(lo, hi);
        }
    };

    // ---- prologue: chunk bc -> Bb[0]; prefetch chunk bc+NBC into regs ----
    load_st(bc);
    conv(0);
    if (bc + NBC < NCHUNK) load_st(bc + NBC);
    asm volatile("s_waitcnt lgkmcnt(0)" ::: "memory");
    __builtin_amdgcn_sched_barrier(0);
    __builtin_amdgcn_s_barrier();
    __builtin_amdgcn_sched_barrier(0);

    int buf = 0;
    for (int ci = bc; ci < NCHUNK; ci += NBC) {
        const int  cn    = ci + NBC;
        const bool hasN  = cn < NCHUNK;
        const bool hasNN = cn + NBC < NCHUNK;

        f4 acc00, acc01, acc10, acc11;
#pragma unroll
        for (int i = 0; i < 4; ++i) {
            acc00[i] = 0.0f; acc01[i] = 0.0f;
            acc10[i] = 0.0f; acc11[i] = 0.0f;
        }
        const char* BB = (const char*)&Bb[buf][0];

        auto kloop = [&]() {
            __builtin_amdgcn_s_setprio(1);
#pragma unroll
            for (int ks = 0; ks < 16; ++ks) {
                int sx = (((ks * 4 + lg) ^ (l15 & 7)) << 4);
                bf8 b0 = *(const bf8*)(BB + l15 * 1024 + sx);
                bf8 b1 = *(const bf8*)(BB + (16 + l15) * 1024 + sx);
                acc00 = __builtin_amdgcn_mfma_f32_16x16x32_bf16(a0[ks], b0, acc00, 0, 0, 0);
                acc01 = __builtin_amdgcn_mfma_f32_16x16x32_bf16(a0[ks], b1, acc01, 0, 0, 0);
                acc10 = __builtin_amdgcn_mfma_f32_16x16x32_bf16(a1[ks], b0, acc10, 0, 0, 0);
                acc11 = __builtin_amdgcn_mfma_f32_16x16x32_bf16(a1[ks], b1, acc11, 0, 0, 0);
            }
            __builtin_amdgcn_s_setprio(0);
        };

        // ---- stagger: odd waves conv-first, even waves kloop-first ----
        if (wv & 1) {
            if (hasN) { conv(buf ^ 1); if (hasNN) load_st(cn + NBC); }
            kloop();
        } else {
            kloop();
            if (hasN) { conv(buf ^ 1); if (hasNN) load_st(cn + NBC); }
        }

        // ---- epilogue: logits ARE acc -> per-lane online (M,S) ----
#pragma unroll
        for (int i = 0; i < 4; ++i) {
            float v0 = acc00[i], v1 = acc01[i];
            float pm = fmaxf(v0, v1);
            float nM = fmaxf(Mr[0][i], pm);
            Sr[0][i] = Sr[0][i] * __expf(Mr[0][i] - nM)
                     + __expf(v0 - nM) + __expf(v1 - nM);
            Mr[0][i] = nM;
            float w0 = acc10[i], w1 = acc11[i];
            float qm = fmaxf(w0, w1);
            float nN = fmaxf(Mr[1][i], qm);
            Sr[1][i] = Sr[1][i] * __expf(Mr[1][i] - nN)
                     + __expf(w0 - nN) + __expf(w1 - nN);
            Mr[1][i] = nN;
        }

        asm volatile("s_waitcnt lgkmcnt(0)" ::: "memory");  // conv writes done
        __builtin_amdgcn_sched_barrier(0);
        __builtin_amdgcn_s_barrier();       // Bb[buf^1] ready, Bb[buf] consumed
        __builtin_amdgcn_sched_barrier(0);
        buf ^= 1;
    }

    // ---- merge (M,S) across the 16 column-lanes, one write per row ----
#pragma unroll
    for (int mf = 0; mf < 2; ++mf)
#pragma unroll
        for (int i = 0; i < 4; ++i) {
            float M = Mr[mf][i], S = Sr[mf][i];
#pragma unroll
            for (int d = 1; d < 16; d <<= 1) {
                float oM = __shfl_xor(M, d), oS = __shfl_xor(S, d);
                float nM = fmaxf(M, oM);
                S = S * __expf(M - nM) + oS * __expf(oM - nM);
                M = nM;
            }
            if (l15 == 0) {
                int m = rg * 256 + wv * 32 + mf * 16 + lg * 4 + i;
                pms[(size_t)bc * BATCH + m] = make_float2(M, S);
            }
        }
}

// ---------------------------------------------------------------------------
// k_fin: merge 128 column-partials per row, patch label col, loss, mean.
// ---------------------------------------------------------------------------
__global__ __launch_bounds__(512) void k_fin(const float2* __restrict__ pms,
                                             const float* __restrict__ tcos,
                                             const float* __restrict__ tphi,
                                             float* __restrict__ out) {
    int t = threadIdx.x;
    float M = -1e38f, S = 0.f;
#pragma unroll 4
    for (int b = 0; b < NBC; ++b) {
        float2 v = pms[(size_t)b * BATCH + t];
        float nM = fmaxf(M, v.x);
        S = S * __expf(M - nM) + v.y * __expf(v.x - nM);
        M = nM;
    }
    float Sc = S - __expf(tcos[t] - M) + __expf(tphi[t] - M);
    Sc = fmaxf(Sc, 1e-30f);
    float loss = M + logf(Sc) - tphi[t];
#pragma unroll
    for (int d = 1; d < 64; d <<= 1) loss += __shfl_xor(loss, d);
    __shared__ float wred[8];
    if ((t & 63) == 0) wred[t >> 6] = loss;
    __syncthreads();
    if (t == 0) {
        float s = 0.f;
        for (int w = 0; w < 8; ++w) s += wred[w];
        out[0] = s / (float)BATCH;
    }
}

extern "C" void kernel_launch(void* const* d_in, const int* in_sizes, int n_in,
                              void* d_out, int out_size, void* d_ws, size_t ws_size,
                              hipStream_t stream) {
    const float*     x     = (const float*)d_in[0];
    const long long* label = (const long long*)d_in[1];
    const float*     W     = (const float*)d_in[2];
    float*           out   = (float*)d_out;

    // workspace layout (~1.1 MB)
    char* ws = (char*)d_ws;
    unsigned short* xb   = (unsigned short*)ws;              // 524288
    float*          tcos = (float*)(ws + 524288);            // 2048
    float*          tphi = (float*)(ws + 526336);            // 2048
    float2*         pms  = (float2*)(ws + 528384);           // 128*512*8 = 524288

    k_normx<<<BATCH / 4, 256, 0, stream>>>(x, xb);
    k_tgt  <<<BATCH / 8, 512, 0, stream>>>(x, W, label, tcos, tphi);
    k_fused<<<GRID_F,    512, 0, stream>>>(W, xb, pms);
    k_fin  <<<1,         512, 0, stream>>>(pms, tcos, tphi, out);
}